// Round 5
// baseline (1856.533 us; speedup 1.0000x reference)
//
#include <hip/hip_runtime.h>
#include <hip/hip_bf16.h>
#include <math.h>

#define B_ 4
#define N_ 8192
#define C_ 128
#define K_ 683
#define KP_ 768
#define KT_ 704   // 11*64 padded K for moments

// ---- workspace layout (float offsets) ----
#define WS_ET      0          // 128*768        = 98304
#define WS_ANCH    98304      // 4*768*4        = 12288
#define WS_EXT     110592     // 4*8192*16      = 524288
#define WS_PART    634880     // 8*4*704*168    = 3784704
#define WS_SUMA    4419584    // 4*704          = 2816
#define WS_NORM    4422400    // 4*704          = 2816
// -- new (MFMA) path --
#define WS_LOSSP2  4425216    // 128 floats (84 tile partials)
#define WS_AT      4425344    // bf16 At[4][768][8192] = 12582912 floats worth
#define WS_NEW_END 17008256   // floats -> 68,033,024 bytes
// -- old (fallback) path --
#define WS_GPART   4425216    // 2*4*768*768    = 4718592
#define WS_LOSSP   9143808    // 512

// ---- output layout (float offsets) ----
#define OUT_A      0
#define OUT_SC     22380544ULL
#define OUT_MUC    22730240ULL
#define OUT_SGC    22738436ULL
#define OUT_TOT    22763024ULL

typedef __attribute__((ext_vector_type(8))) short bf16x8s;
typedef __attribute__((ext_vector_type(4))) float f32x4;

static __device__ __forceinline__ unsigned short f2bf_rne(float f) {
  unsigned int u = __builtin_bit_cast(unsigned int, f);
  unsigned int r = (u + 0x7fffu + ((u >> 16) & 1u)) >> 16;
  return (unsigned short)r;
}

// =====================================================================
// E[k,c] = sum_d slot_embed[k,d] * W_proj[d,c], stored as ET[c][k]
__global__ __launch_bounds__(256) void build_ET_k(const float* __restrict__ Wp,
                                                  const float* __restrict__ se,
                                                  float* __restrict__ ET) {
  int idx = blockIdx.x * 256 + threadIdx.x;
  if (idx >= C_ * KP_) return;
  int c = idx / KP_;
  int k = idx % KP_;
  float acc = 0.f;
  if (k < K_) {
    for (int d = 0; d < C_; d++) acc = fmaf(se[k * C_ + d], Wp[d * C_ + c], acc);
  }
  ET[idx] = acc;
}

// =====================================================================
// FUSED kernel, 512 threads/block:
//   blocks 0..3      : FPS (one per batch) -> anchors
//   blocks 4..1027   : semantic GEMM, 32 rows each -> Lsem into A region
//   blocks 1028..1091: build ext features
// launch_bounds(512,2): VGPR cap 256 so the FPS register arrays (64 VGPRs)
// stay resident — with the default cap the allocator sized for the GEMM
// branch (88 VGPR) and spilled FPS's md/px/py/pz to scratch, putting
// ~L2-latency scratch round-trips on the 682-iteration serial path.
__global__ __launch_bounds__(512, 2) void fused_k(const float* __restrict__ s,
    const float* __restrict__ mu, const float* __restrict__ Sigma,
    const float* __restrict__ mask, const float* __restrict__ ET,
    float* __restrict__ anchors, float* __restrict__ ext,
    float* __restrict__ A) {
  const int bid = blockIdx.x;
  const int tid = threadIdx.x;

  __shared__ __align__(16) float s_lds[32][132];
  __shared__ __align__(16) float et_lds[8][KP_];
  __shared__ double redd[8][4];
  __shared__ float redv[2][8];
  __shared__ int redi[2][8];
  __shared__ float an_s[4];

  if (bid >= 1028) {
    int idx = (bid - 1028) * 512 + tid;
    if (idx < B_ * N_) {
      float x = mu[(size_t)idx * 3 + 0];
      float y = mu[(size_t)idx * 3 + 1];
      float z = mu[(size_t)idx * 3 + 2];
      const float* S = Sigma + (size_t)idx * 9;
      float* e = ext + (size_t)idx * 16;
      e[0] = x; e[1] = y; e[2] = z;
      e[3] = x * x; e[4] = x * y; e[5] = x * z;
      e[6] = y * y; e[7] = y * z; e[8] = z * z;
      e[9] = S[0]; e[10] = S[1]; e[11] = S[2]; e[12] = S[4]; e[13] = S[5]; e[14] = S[8];
      e[15] = 1.f;
    }
    return;
  }

  if (bid >= 4) {
    const int gb = bid - 4;
    const int b = gb >> 8;
    const int n0 = (gb & 255) * 32;
    const int nt = tid >> 6;
    const int kt = tid & 63;
    {
      const float* sb = s + ((size_t)(b * N_ + n0)) * C_;
      int r = tid >> 4;
      int cb = (tid & 15) * 8;
#pragma unroll
      for (int q = 0; q < 2; q++) {
        float4 v = *(const float4*)(sb + (size_t)r * C_ + cb + q * 4);
        *(float4*)(&s_lds[r][cb + q * 4]) = v;
      }
    }
    float acc[4][12];
#pragma unroll
    for (int i = 0; i < 4; i++)
#pragma unroll
      for (int j = 0; j < 12; j++) acc[i][j] = 0.f;

    for (int cc = 0; cc < 16; cc++) {
      __syncthreads();
#pragma unroll
      for (int q = 0; q < 3; q++) {
        int fid = q * 512 + tid;
        int cl = fid / 192;
        int o4 = fid % 192;
        *(float4*)(&et_lds[cl][o4 * 4]) = *(const float4*)(ET + (size_t)(cc * 8 + cl) * KP_ + o4 * 4);
      }
      __syncthreads();
#pragma unroll
      for (int c8 = 0; c8 < 8; c8++) {
        int c = cc * 8 + c8;
        float sv0 = s_lds[nt * 4 + 0][c];
        float sv1 = s_lds[nt * 4 + 1][c];
        float sv2 = s_lds[nt * 4 + 2][c];
        float sv3 = s_lds[nt * 4 + 3][c];
#pragma unroll
        for (int j = 0; j < 12; j++) {
          float ev = et_lds[c8][kt + 64 * j];
          acc[0][j] = fmaf(sv0, ev, acc[0][j]);
          acc[1][j] = fmaf(sv1, ev, acc[1][j]);
          acc[2][j] = fmaf(sv2, ev, acc[2][j]);
          acc[3][j] = fmaf(sv3, ev, acc[3][j]);
        }
      }
    }
#pragma unroll
    for (int i = 0; i < 4; i++) {
      float* Arow = A + ((size_t)(b * N_ + n0 + nt * 4 + i)) * K_;
#pragma unroll
      for (int j = 0; j < 12; j++) {
        int k = kt + 64 * j;
        if (k < K_) Arow[k] = acc[i][j];
      }
    }
    return;
  }

  // ---------------- FPS ----------------
  const int b = bid;
  const int t = tid;
  const int wv = t >> 6;
  const float* mub = mu + (size_t)b * N_ * 3;
  const float* mkb = mask + (size_t)b * N_;
  // register arrays: 64 VGPRs total. md encodes mask: -1 = masked (absorbing
  // under fminf since d2 >= 0), +3.4e38 = valid-but-uninitialized (first
  // update yields d2-to-anchor0, matching the reference min_d2 init).
  float px[16], py[16], pz[16], md[16];

  double sx = 0, sy = 0, sz = 0, sc = 0;
#pragma unroll
  for (int i = 0; i < 16; i++) {
    int p = i * 512 + t;
    px[i] = mub[p * 3 + 0];
    py[i] = mub[p * 3 + 1];
    pz[i] = mub[p * 3 + 2];
    float mk = mkb[p];
    bool valid = (mk > 0.5f);
    md[i] = valid ? 3.4e38f : -1.f;
    if (valid) { sx += px[i]; sy += py[i]; sz += pz[i]; sc += 1.0; }
  }
  for (int off = 32; off; off >>= 1) {
    sx += __shfl_xor(sx, off);
    sy += __shfl_xor(sy, off);
    sz += __shfl_xor(sz, off);
    sc += __shfl_xor(sc, off);
  }
  if ((t & 63) == 0) { redd[wv][0] = sx; redd[wv][1] = sy; redd[wv][2] = sz; redd[wv][3] = sc; }
  __syncthreads();
  if (t == 0) {
    double ax = 0, ay = 0, az = 0, ac = 0;
    for (int w = 0; w < 8; w++) { ax += redd[w][0]; ay += redd[w][1]; az += redd[w][2]; ac += redd[w][3]; }
    if (ac < 1.0) ac = 1.0;
    an_s[0] = (float)(ax / ac); an_s[1] = (float)(ay / ac); an_s[2] = (float)(az / ac);
  }
  __syncthreads();

  float ax, ay, az;
  {
    float cx = an_s[0], cy = an_s[1], cz = an_s[2];
    float bv = -2.f, bv2 = -2.f; int bi = 0, bi2 = 0;
#pragma unroll
    for (int i = 0; i < 16; i++) {
      float dx = px[i] - cx, dy = py[i] - cy, dz = pz[i] - cz;
      float d2 = __fadd_rn(__fadd_rn(__fmul_rn(dx, dx), __fmul_rn(dy, dy)), __fmul_rn(dz, dz));
      float v = (md[i] < 0.f) ? -1.f : d2;
      if (i & 1) { if (v > bv2) { bv2 = v; bi2 = i * 512 + t; } }
      else       { if (v > bv)  { bv = v;  bi = i * 512 + t; } }
    }
    if (bv2 > bv || (bv2 == bv && bi2 < bi)) { bv = bv2; bi = bi2; }
    for (int off = 32; off; off >>= 1) {
      float ov = __shfl_xor(bv, off); int oi = __shfl_xor(bi, off);
      if (ov > bv || (ov == bv && oi < bi)) { bv = ov; bi = oi; }
    }
    if ((t & 63) == 0) { redv[0][wv] = bv; redi[0][wv] = bi; }
    __syncthreads();
    float bestv = redv[0][0]; int besti = redi[0][0];
#pragma unroll
    for (int w = 1; w < 8; w++) {
      float ov = redv[0][w]; int oi = redi[0][w];
      if (ov > bestv || (ov == bestv && oi < besti)) { bestv = ov; besti = oi; }
    }
    ax = mub[besti * 3 + 0]; ay = mub[besti * 3 + 1]; az = mub[besti * 3 + 2];
    if (t == 0) {
      float aa = ax * ax + ay * ay + az * az;
      float4 st = {ax, ay, az, aa};
      *(float4*)(anchors + ((size_t)b * KP_ + 0) * 4) = st;
    }
  }

  for (int k = 1; k < K_; k++) {
    const int par = k & 1;
    float bv = -2.f, bv2 = -2.f; int bi = 0, bi2 = 0;
#pragma unroll
    for (int i = 0; i < 16; i++) {
      float dx = px[i] - ax, dy = py[i] - ay, dz = pz[i] - az;
      float d2 = __fadd_rn(__fadd_rn(__fmul_rn(dx, dx), __fmul_rn(dy, dy)), __fmul_rn(dz, dz));
      float m = fminf(md[i], d2);
      md[i] = m;
      if (i & 1) { if (m > bv2) { bv2 = m; bi2 = i * 512 + t; } }
      else       { if (m > bv)  { bv = m;  bi = i * 512 + t; } }
    }
    if (bv2 > bv || (bv2 == bv && bi2 < bi)) { bv = bv2; bi = bi2; }
    for (int off = 32; off; off >>= 1) {
      float ov = __shfl_xor(bv, off); int oi = __shfl_xor(bi, off);
      if (ov > bv || (ov == bv && oi < bi)) { bv = ov; bi = oi; }
    }
    if ((t & 63) == 0) { redv[par][wv] = bv; redi[par][wv] = bi; }
    __syncthreads();
    float bestv = redv[par][0]; int besti = redi[par][0];
#pragma unroll
    for (int w = 1; w < 8; w++) {
      float ov = redv[par][w]; int oi = redi[par][w];
      if (ov > bestv || (ov == bestv && oi < besti)) { bestv = ov; besti = oi; }
    }
    ax = mub[besti * 3 + 0]; ay = mub[besti * 3 + 1]; az = mub[besti * 3 + 2];
    if (t == 0) {
      float aa = ax * ax + ay * ay + az * az;
      float4 st = {ax, ay, az, aa};
      *(float4*)(anchors + ((size_t)b * KP_ + k) * 4) = st;
    }
  }
  for (int k = K_ + t; k < KP_; k += 512) {
    float4 z4 = {0.f, 0.f, 0.f, 0.f};
    *(float4*)(anchors + ((size_t)b * KP_ + k) * 4) = z4;
  }
}

// =====================================================================
// spatial logits + mask + softmax, in place over A (holds Lsem).
__global__ __launch_bounds__(256) void spatial_softmax_k(
    const float* __restrict__ mu, const float* __restrict__ mask,
    const float* __restrict__ anchors, const float* __restrict__ lsm_p,
    const float* __restrict__ wsem_p, const float* __restrict__ wmu_p,
    float* __restrict__ A) {
  const int bid = blockIdx.x;
  const int b = bid >> 11;
  const int n0 = (bid & 2047) * 4;
  const int tid = threadIdx.x;
  const int wv = tid >> 6;
  const int lane = tid & 63;
  __shared__ __align__(16) float anch_lds[KP_][4];
  for (int q = tid; q < KP_; q += 256)
    *(float4*)(&anch_lds[q][0]) = *(const float4*)(anchors + ((size_t)b * KP_ + q) * 4);
  __syncthreads();

  const float sg = fmaxf(expf(lsm_p[0]), 1e-4f);
  const float inv2s2 = 0.5f / (sg * sg);
  const float wsem = wsem_p[0];
  const float wmu = wmu_p[0];

  const size_t gr = (size_t)b * N_ + n0 + wv;
  const float* mp = mu + gr * 3;
  float x = mp[0], y = mp[1], z = mp[2];
  float mq = x * x + y * y + z * z;
  float mk = mask[gr];
  float* Arow = A + gr * K_;

  float v[11];
  float m = -3e38f;
#pragma unroll
  for (int j = 0; j < 11; j++) {
    int k = lane + 64 * j;
    if (k < K_) {
      float lsem = Arow[k];
      float4 a4 = *(const float4*)(&anch_lds[k][0]);
      float tdot = x * a4.x + y * a4.y + z * a4.z;
      float d2 = mq - 2.f * tdot + a4.w;
      float l = wsem * lsem - wmu * d2 * inv2s2;
      if (mk < 0.5f) l = -1e9f;
      v[j] = l;
    } else v[j] = -1e30f;
    m = fmaxf(m, v[j]);
  }
  for (int off = 32; off; off >>= 1) m = fmaxf(m, __shfl_xor(m, off));
  float sum = 0.f;
#pragma unroll
  for (int j = 0; j < 11; j++) { float e = expf(v[j] - m); v[j] = e; sum += e; }
  for (int off = 32; off; off >>= 1) sum += __shfl_xor(sum, off);
  float r = mk / sum;
#pragma unroll
  for (int j = 0; j < 11; j++) {
    int k = lane + 64 * j;
    if (k < K_) Arow[k] = v[j] * r;
  }
}

// =====================================================================
// Transpose A fp32 [b][n][683] -> At bf16 [b][768][8192] (pad rows zero)
__global__ __launch_bounds__(256) void transpose_at_k(const float* __restrict__ A,
    unsigned short* __restrict__ At) {
  const int bid = blockIdx.x;          // b(4) * ktile(12) * ntile(128)
  const int ntile = bid % 128;
  const int rem = bid / 128;
  const int kt = rem % 12;
  const int b = rem / 12;
  const int k0 = kt * 64, n0 = ntile * 64;
  const int tid = threadIdx.x;
  __shared__ __align__(16) unsigned short T[64][72];

  {
    const int n_loc = tid >> 4;        // 0..15
    const int k4 = (tid & 15) * 4;
#pragma unroll
    for (int nn = 0; nn < 4; nn++) {
      int n = n_loc + 16 * nn;
      const float* ar = A + ((size_t)(b * N_ + n0 + n)) * K_;
#pragma unroll
      for (int q = 0; q < 4; q++) {
        int kk = k0 + k4 + q;
        float f = (kk < K_) ? ar[kk] : 0.f;
        T[k4 + q][n] = f2bf_rne(f);
      }
    }
  }
  __syncthreads();
  {
    const int k_loc = tid >> 2;        // 0..63
    const int c = tid & 3;             // 16-ushort chunk
    uint4 v0 = *(const uint4*)(&T[k_loc][c * 16]);
    uint4 v1 = *(const uint4*)(&T[k_loc][c * 16 + 8]);
    unsigned short* dst = At + ((size_t)(b * KP_ + k0 + k_loc)) * N_ + n0 + c * 16;
    *(uint4*)dst = v0;
    *(uint4*)(dst + 8) = v1;
  }
}

// =====================================================================
// MFMA gram + fused collapse-loss tile partial.
// 84 blocks = 4 b x 21 symmetric 128x128 tiles; full N reduction per block.
__global__ __launch_bounds__(256) void gram_mfma_k(const unsigned short* __restrict__ At,
    const float* __restrict__ norm_ws, float* __restrict__ lossp) {
  const int bid = blockIdx.x;
  const int b = bid / 21;
  int p = bid % 21;
  int tk = 0, tl = 0;
  { int pp = p; for (int r0 = 0; r0 < 6; r0++) { int cnt = 6 - r0; if (pp < cnt) { tk = r0; tl = r0 + pp; break; } pp -= cnt; } }
  const int k0 = tk * 128, l0 = tl * 128;
  const int tid = threadIdx.x;
  const int l = tid & 63;
  const int w = tid >> 6;
  const int wr = w >> 1, wc = w & 1;

  __shared__ __align__(16) unsigned short Ak_lds[128 * 72];
  __shared__ __align__(16) unsigned short Al_lds[128 * 72];
  __shared__ float nk_s[128], nl_s[128], red_s[4];

  if (tid < 128) {
    int kk = k0 + tid;
    nk_s[tid] = (kk < K_) ? fmaxf(norm_ws[b * KT_ + kk], 1e-8f) : 1.f;
  } else {
    int ll2 = l0 + tid - 128;
    nl_s[tid - 128] = (ll2 < K_) ? fmaxf(norm_ws[b * KT_ + ll2], 1e-8f) : 1.f;
  }

  f32x4 acc[4][4];
#pragma unroll
  for (int i = 0; i < 4; i++)
#pragma unroll
    for (int j = 0; j < 4; j++) acc[i][j] = (f32x4){0.f, 0.f, 0.f, 0.f};

  const unsigned short* gk = At + ((size_t)(b * KP_ + k0)) * N_;
  const unsigned short* gl = At + ((size_t)(b * KP_ + l0)) * N_;

  for (int ch = 0; ch < 128; ch++) {
    const int n0 = ch * 64;
    __syncthreads();
#pragma unroll
    for (int q = 0; q < 4; q++) {
      int chunk = tid + 256 * q;
      int row = chunk >> 3, slot = chunk & 7;
      uint4 v = *(const uint4*)(gk + (size_t)row * N_ + n0 + slot * 8);
      *(uint4*)(Ak_lds + row * 72 + slot * 8) = v;
      uint4 v2 = *(const uint4*)(gl + (size_t)row * N_ + n0 + slot * 8);
      *(uint4*)(Al_lds + row * 72 + slot * 8) = v2;
    }
    __syncthreads();
#pragma unroll
    for (int ks = 0; ks < 2; ks++) {
      const int noff = (l >> 4) * 8 + ks * 32;
      bf16x8s af[4], bfr[4];
#pragma unroll
      for (int f = 0; f < 4; f++) {
        af[f]  = *(const bf16x8s*)(Ak_lds + (wr * 64 + f * 16 + (l & 15)) * 72 + noff);
        bfr[f] = *(const bf16x8s*)(Al_lds + (wc * 64 + f * 16 + (l & 15)) * 72 + noff);
      }
#pragma unroll
      for (int i = 0; i < 4; i++)
#pragma unroll
        for (int j = 0; j < 4; j++)
          acc[i][j] = __builtin_amdgcn_mfma_f32_16x16x32_bf16(af[i], bfr[j], acc[i][j], 0, 0, 0);
    }
  }

  // epilogue: loss partial for this tile
  float local = 0.f;
  const float wgt = (tk == tl) ? 1.f : 2.f;
#pragma unroll
  for (int i = 0; i < 4; i++) {
#pragma unroll
    for (int j = 0; j < 4; j++) {
#pragma unroll
      for (int r = 0; r < 4; r++) {
        int ki = wr * 64 + i * 16 + (l >> 4) * 4 + r;   // local row
        int li = wc * 64 + j * 16 + (l & 15);           // local col
        int gkk = k0 + ki, gll = l0 + li;
        if (gkk < K_ && gll < K_ && gkk != gll) {
          float g = acc[i][j][r];
          float x = g / (nk_s[ki] * nl_s[li]);
          local = fmaf(wgt * x, x, local);
        }
      }
    }
  }
  for (int off = 32; off; off >>= 1) local += __shfl_xor(local, off);
  if ((tid & 63) == 0) red_s[w] = local;
  __syncthreads();
  if (tid == 0) lossp[bid] = red_s[0] + red_s[1] + red_s[2] + red_s[3];
}

// =====================================================================
// GEMM2: moments = A^T x F, F = [s(128) | ext(16) | pad(16)], plus sum(A^2).
__global__ __launch_bounds__(256) void gemm2_k(const float* __restrict__ A,
    const float* __restrict__ s, const float* __restrict__ ext,
    float* __restrict__ part) {
  const int bid = blockIdx.x;
  const int np = bid / 44;
  const int rem = bid % 44;
  const int b = rem / 11;
  const int k0 = (rem % 11) * 64;
  const int n0 = np * 1024;
  const int tid = threadIdx.x;
  const int kt = tid & 15;
  const int ft = tid >> 4;
  __shared__ __align__(16) float A_lds[32][64];
  __shared__ __align__(16) float F_lds[32][160];
  float acc[4][10];
#pragma unroll
  for (int c = 0; c < 4; c++)
#pragma unroll
    for (int f = 0; f < 10; f++) acc[c][f] = 0.f;
  float asq[4] = {0.f, 0.f, 0.f, 0.f};

  for (int ch = 0; ch < 32; ch++) {
    int nb = n0 + ch * 32;
    __syncthreads();
#pragma unroll
    for (int p = 0; p < 8; p++) {
      int q = tid + 256 * p; int r = q >> 6; int c = q & 63; int k = k0 + c;
      A_lds[r][c] = (k < K_) ? A[((size_t)(b * N_ + nb + r)) * K_ + k] : 0.f;
    }
#pragma unroll
    for (int p = 0; p < 16; p++) {
      int q = tid + 256 * p; int r = q >> 7; int c = q & 127;
      F_lds[r][c] = s[((size_t)(b * N_ + nb + r)) * C_ + c];
    }
#pragma unroll
    for (int p = 0; p < 2; p++) {
      int q = tid + 256 * p; int r = q >> 4; int e = q & 15;
      F_lds[r][128 + e] = ext[((size_t)(b * N_ + nb + r)) * 16 + e];
      F_lds[r][144 + e] = 0.f;
    }
    __syncthreads();
#pragma unroll
    for (int i = 0; i < 32; i++) {
      float a0 = A_lds[i][kt * 4 + 0];
      float a1 = A_lds[i][kt * 4 + 1];
      float a2 = A_lds[i][kt * 4 + 2];
      float a3 = A_lds[i][kt * 4 + 3];
      if (ft == 0) {
        asq[0] = fmaf(a0, a0, asq[0]); asq[1] = fmaf(a1, a1, asq[1]);
        asq[2] = fmaf(a2, a2, asq[2]); asq[3] = fmaf(a3, a3, asq[3]);
      }
#pragma unroll
      for (int f = 0; f < 10; f++) {
        float fv = F_lds[i][ft * 10 + f];
        acc[0][f] = fmaf(a0, fv, acc[0][f]);
        acc[1][f] = fmaf(a1, fv, acc[1][f]);
        acc[2][f] = fmaf(a2, fv, acc[2][f]);
        acc[3][f] = fmaf(a3, fv, acc[3][f]);
      }
    }
  }
#pragma unroll
  for (int c = 0; c < 4; c++) {
    size_t base = ((size_t)((np * 4 + b) * KT_ + k0 + kt * 4 + c)) * 168;
#pragma unroll
    for (int f = 0; f < 10; f++) part[base + ft * 10 + f] = acc[c][f];
    if (ft == 0) part[base + 160] = asq[c];
  }
}

// =====================================================================
// Postprocess: one wave per (b,k): s_c, mu_c, Sigma_c, sumA, norms.
__global__ __launch_bounds__(256) void postproc_k(const float* __restrict__ part,
    float* __restrict__ out, float* __restrict__ sumA_ws, float* __restrict__ norm_ws) {
  const int gw = blockIdx.x * 4 + (threadIdx.x >> 6);
  const int lane = threadIdx.x & 63;
  const int b = gw / K_;
  const int k = gw % K_;
  float v0 = 0.f, v1 = 0.f, v2 = 0.f, v3 = 0.f;
  for (int np = 0; np < 8; np++) {
    const float* r = part + ((size_t)((np * 4 + b) * KT_ + k)) * 168;
    v0 += r[lane];
    v1 += r[64 + lane];
    if (lane < 16) v2 += r[128 + lane];
    if (lane == 0) v3 += r[160];
  }
  float sumA = __shfl(v2, 15);
  float asq = __shfl(v3, 0);
  float denom = fmaxf(sumA, 1e-8f);
  float inv = 1.f / denom;
  out[OUT_SC + ((size_t)(b * K_ + k)) * C_ + lane] = v0 * inv;
  out[OUT_SC + ((size_t)(b * K_ + k)) * C_ + 64 + lane] = v1 * inv;
  float m0 = __shfl(v2, 0) * inv;
  float m1 = __shfl(v2, 1) * inv;
  float m2 = __shfl(v2, 2) * inv;
  if (lane < 3) out[OUT_MUC + ((size_t)(b * K_ + k)) * 3 + lane] = (lane == 0) ? m0 : ((lane == 1) ? m1 : m2);
  float W = sumA * inv;
  float fac = 2.f - W;
  float M2s[6], Sgs[6];
#pragma unroll
  for (int j = 0; j < 6; j++) { M2s[j] = __shfl(v2, 3 + j); Sgs[j] = __shfl(v2, 9 + j); }
  if (lane < 9) {
    int d = lane / 3, e = lane % 3;
    int lo = min(d, e), hi = max(d, e);
    int j = hi + 2 * lo - ((lo * (lo - 1)) >> 1);
    float mud = (d == 0) ? m0 : ((d == 1) ? m1 : m2);
    float mue = (e == 0) ? m0 : ((e == 1) ? m1 : m2);
    float M2j = (j == 0) ? M2s[0] : (j == 1) ? M2s[1] : (j == 2) ? M2s[2] : (j == 3) ? M2s[3] : (j == 4) ? M2s[4] : M2s[5];
    float Sgj = (j == 0) ? Sgs[0] : (j == 1) ? Sgs[1] : (j == 2) ? Sgs[2] : (j == 3) ? Sgs[3] : (j == 4) ? Sgs[4] : Sgs[5];
    float val = (Sgj + M2j) * inv - mud * mue * fac;
    if (d == e) val += 1e-6f;
    out[OUT_SGC + ((size_t)(b * K_ + k)) * 9 + lane] = val;
  }
  if (lane == 0) { sumA_ws[b * KT_ + k] = sumA; norm_ws[b * KT_ + k] = sqrtf(asq); }
}

// =====================================================================
// OLD fp32 gram path (fallback if ws too small for At)
__device__ __forceinline__ int swz(int f) { return f ^ (((f >> 5) & 3) << 3); }

__global__ __launch_bounds__(256) void gram_k(const float* __restrict__ A,
                                              float* __restrict__ Gpart) {
  const int bid = blockIdx.x;
  const int np = bid & 1;
  int q = bid >> 1;
  const int b = q / 21;
  int p = q % 21;
  int tk = 0, tl = 0;
  { int pp = p; for (int r0 = 0; r0 < 6; r0++) { int cnt = 6 - r0; if (pp < cnt) { tk = r0; tl = r0 + pp; break; } pp -= cnt; } }
  const int k0 = tk * 128, l0 = tl * 128;
  const int n0 = np * 4096;
  const int tid = threadIdx.x;
  const int ktid = tid & 15, ltid = tid >> 4;
  const bool diag = (tk == tl);
  __shared__ __align__(16) float Ak[32][128];
  __shared__ __align__(16) float Al[32][128];
  float acc[8][8];
#pragma unroll
  for (int i = 0; i < 8; i++)
#pragma unroll
    for (int j = 0; j < 8; j++) acc[i][j] = 0.f;

  const int kb = swz(ktid * 8);
  const int lb = swz(ltid * 8);
  for (int ch = 0; ch < 128; ch++) {
    int nb = n0 + ch * 32;
    __syncthreads();
#pragma unroll
    for (int pq = 0; pq < 16; pq++) {
      int qq = tid + 256 * pq; int r = qq >> 7; int c = qq & 127;
      int kk = k0 + c;
      Ak[r][swz(c)] = (kk < K_) ? A[((size_t)(b * N_ + nb + r)) * K_ + kk] : 0.f;
      if (!diag) {
        int ll = l0 + c;
        Al[r][swz(c)] = (ll < K_) ? A[((size_t)(b * N_ + nb + r)) * K_ + ll] : 0.f;
      }
    }
    __syncthreads();
    const float (*Alp)[128] = diag ? Ak : Al;
#pragma unroll
    for (int i = 0; i < 32; i++) {
      float4 ka = *(const float4*)(&Ak[i][kb]);
      float4 kb4 = *(const float4*)(&Ak[i][kb + 4]);
      float4 la = *(const float4*)(&Alp[i][lb]);
      float4 lb4 = *(const float4*)(&Alp[i][lb + 4]);
      float av[8] = {ka.x, ka.y, ka.z, ka.w, kb4.x, kb4.y, kb4.z, kb4.w};
      float lv[8] = {la.x, la.y, la.z, la.w, lb4.x, lb4.y, lb4.z, lb4.w};
#pragma unroll
      for (int ii = 0; ii < 8; ii++)
#pragma unroll
        for (int jj = 0; jj < 8; jj++)
          acc[ii][jj] = fmaf(av[ii], lv[jj], acc[ii][jj]);
    }
  }
#pragma unroll
  for (int ii = 0; ii < 8; ii++) {
    int kk = k0 + ktid * 8 + ii;
    float* gp = Gpart + ((size_t)((np * 4 + b) * KP_ + kk)) * KP_ + l0 + ltid * 8;
#pragma unroll
    for (int jj = 0; jj < 8; jj++) gp[jj] = acc[ii][jj];
  }
}

__global__ __launch_bounds__(256) void loss_part_k(const float* __restrict__ Gpart,
    const float* __restrict__ norm_ws, float* __restrict__ lossp) {
  const long long total = (long long)B_ * 21 * 16384;
  float local = 0.f;
  for (long long idx = (long long)blockIdx.x * 256 + threadIdx.x; idx < total; idx += (long long)512 * 256) {
    int e = (int)(idx & 16383);
    int rest = (int)(idx >> 14);
    int p = rest % 21;
    int b = rest / 21;
    int tk = 0, tl = 0;
    { int pp = p; for (int r0 = 0; r0 < 6; r0++) { int cnt = 6 - r0; if (pp < cnt) { tk = r0; tl = r0 + pp; break; } pp -= cnt; } }
    int i = e >> 7, j = e & 127;
    int k = tk * 128 + i, l = tl * 128 + j;
    if (k < K_ && l < K_ && k != l) {
      size_t i0 = ((size_t)((0 * 4 + b) * KP_ + k)) * KP_ + l;
      size_t i1 = ((size_t)((1 * 4 + b) * KP_ + k)) * KP_ + l;
      float g = Gpart[i0] + Gpart[i1];
      float nk = fmaxf(norm_ws[b * KT_ + k], 1e-8f);
      float nl2 = fmaxf(norm_ws[b * KT_ + l], 1e-8f);
      float x = g / (nk * nl2);
      float wgt = (tk == tl) ? 1.f : 2.f;
      local = fmaf(wgt * x, x, local);
    }
  }
  __shared__ float red[4];
  for (int off = 32; off; off >>= 1) local += __shfl_xor(local, off);
  if ((threadIdx.x & 63) == 0) red[threadIdx.x >> 6] = local;
  __syncthreads();
  if (threadIdx.x == 0) lossp[blockIdx.x] = red[0] + red[1] + red[2] + red[3];
}

__global__ __launch_bounds__(256) void final_k(const float* __restrict__ sumA_ws,
    const float* __restrict__ lossp, float* __restrict__ out) {
  const int lane = threadIdx.x & 63;
  const int wv = threadIdx.x >> 6;
  __shared__ float occ_s[4];
  __shared__ float col_s[4];
  float sb = 0.f;
  for (int k = lane; k < K_; k += 64) sb += sumA_ws[wv * KT_ + k];
  for (int off = 32; off; off >>= 1) sb += __shfl_xor(sb, off);
  float Sb = fmaxf(sb, 1e-8f);
  float lo = 0.f;
  const float tgt = 1.f / (float)K_;
  for (int k = lane; k < K_; k += 64) {
    float o = sumA_ws[wv * KT_ + k] / Sb - tgt;
    lo = fmaf(o, o, lo);
  }
  for (int off = 32; off; off >>= 1) lo += __shfl_xor(lo, off);
  if (lane == 0) occ_s[wv] = lo;
  float c = lossp[threadIdx.x] + lossp[threadIdx.x + 256];
  for (int off = 32; off; off >>= 1) c += __shfl_xor(c, off);
  if (lane == 0) col_s[wv] = c;
  __syncthreads();
  if (threadIdx.x == 0) {
    float loss_occ = (occ_s[0] + occ_s[1] + occ_s[2] + occ_s[3]) / (float)(B_ * K_);
    float coll = (col_s[0] + col_s[1] + col_s[2] + col_s[3]) / ((float)B_ * K_ * K_);
    out[OUT_TOT] = loss_occ + 0.1f * coll;
  }
}

// final for the MFMA path: 84 tile partials
__global__ __launch_bounds__(256) void final2_k(const float* __restrict__ sumA_ws,
    const float* __restrict__ lossp, float* __restrict__ out) {
  const int lane = threadIdx.x & 63;
  const int wv = threadIdx.x >> 6;
  __shared__ float occ_s[4];
  __shared__ float col_s[4];
  float sb = 0.f;
  for (int k = lane; k < K_; k += 64) sb += sumA_ws[wv * KT_ + k];
  for (int off = 32; off; off >>= 1) sb += __shfl_xor(sb, off);
  float Sb = fmaxf(sb, 1e-8f);
  float lo = 0.f;
  const float tgt = 1.f / (float)K_;
  for (int k = lane; k < K_; k += 64) {
    float o = sumA_ws[wv * KT_ + k] / Sb - tgt;
    lo = fmaf(o, o, lo);
  }
  for (int off = 32; off; off >>= 1) lo += __shfl_xor(lo, off);
  if (lane == 0) occ_s[wv] = lo;
  float c = 0.f;
  for (int i = threadIdx.x; i < 84; i += 256) c += lossp[i];
  for (int off = 32; off; off >>= 1) c += __shfl_xor(c, off);
  if (lane == 0) col_s[wv] = c;
  __syncthreads();
  if (threadIdx.x == 0) {
    float loss_occ = (occ_s[0] + occ_s[1] + occ_s[2] + occ_s[3]) / (float)(B_ * K_);
    float coll = (col_s[0] + col_s[1] + col_s[2] + col_s[3]) / ((float)B_ * K_ * K_);
    out[OUT_TOT] = loss_occ + 0.1f * coll;
  }
}

// =====================================================================
extern "C" void kernel_launch(void* const* d_in, const int* in_sizes, int n_in,
                              void* d_out, int out_size, void* d_ws, size_t ws_size,
                              hipStream_t stream) {
  const float* s = (const float*)d_in[0];
  const float* mu = (const float*)d_in[1];
  const float* Sigma = (const float*)d_in[2];
  const float* mask = (const float*)d_in[3];
  const float* Wp = (const float*)d_in[4];
  const float* se = (const float*)d_in[5];
  const float* lsm = (const float*)d_in[6];
  const float* wsem = (const float*)d_in[7];
  const float* wmu = (const float*)d_in[8];
  float* out = (float*)d_out;
  float* ws = (float*)d_ws;

  float* ET = ws + WS_ET;
  float* anch = ws + WS_ANCH;
  float* ext = ws + WS_EXT;
  float* part = ws + WS_PART;
  float* sumA = ws + WS_SUMA;
  float* nrm = ws + WS_NORM;

  hipLaunchKernelGGL(build_ET_k, dim3(384), dim3(256), 0, stream, Wp, se, ET);
  hipLaunchKernelGGL(fused_k, dim3(1092), dim3(512), 0, stream, s, mu, Sigma, mask, ET, anch, ext, out);
  hipLaunchKernelGGL(spatial_softmax_k, dim3(8192), dim3(256), 0, stream, mu, mask, anch, lsm, wsem, wmu, out);
  hipLaunchKernelGGL(gemm2_k, dim3(352), dim3(256), 0, stream, out, s, ext, part);
  hipLaunchKernelGGL(postproc_k, dim3(683), dim3(256), 0, stream, part, out, sumA, nrm);

  const bool use_mfma = ws_size >= (size_t)WS_NEW_END * 4;
  if (use_mfma) {
    float* lossp2 = ws + WS_LOSSP2;
    unsigned short* At = (unsigned short*)(ws + WS_AT);
    hipLaunchKernelGGL(transpose_at_k, dim3(4 * 12 * 128), dim3(256), 0, stream, out, At);
    hipLaunchKernelGGL(gram_mfma_k, dim3(84), dim3(256), 0, stream, At, nrm, lossp2);
    hipLaunchKernelGGL(final2_k, dim3(1), dim3(256), 0, stream, sumA, lossp2, out);
  } else {
    float* Gpart = ws + WS_GPART;
    float* lossp = ws + WS_LOSSP;
    hipLaunchKernelGGL(gram_k, dim3(168), dim3(256), 0, stream, out, Gpart);
    hipLaunchKernelGGL(loss_part_k, dim3(512), dim3(256), 0, stream, Gpart, nrm, lossp);
    hipLaunchKernelGGL(final_k, dim3(1), dim3(256), 0, stream, sumA, lossp, out);
  }
}

// Round 6
// 1738.543 us; speedup vs baseline: 1.0679x; 1.0679x over previous
//
#include <hip/hip_runtime.h>
#include <hip/hip_bf16.h>
#include <math.h>

#define B_ 4
#define N_ 8192
#define C_ 128
#define K_ 683
#define KP_ 768
#define KT_ 704   // 11*64 padded K for moments

// ---- workspace layout (float offsets) ----
#define WS_ET      0          // 128*768        = 98304
#define WS_ANCH    98304      // 4*768*4        = 12288
#define WS_EXT     110592     // 4*8192*16      = 524288
#define WS_PART    634880     // 8*4*704*168    = 3784704
#define WS_SUMA    4419584    // 4*704          = 2816
#define WS_NORM    4422400    // 4*704          = 2816
// -- new (MFMA) path --
#define WS_LOSSP2  4425216    // 128 floats (84 tile partials)
#define WS_AT      4425344    // bf16 At[4][768][8192] = 12582912 floats worth
#define WS_NEW_END 17008256   // floats -> 68,033,024 bytes
// -- old (fallback) path --
#define WS_GPART   4425216    // 2*4*768*768    = 4718592
#define WS_LOSSP   9143808    // 512

// ---- output layout (float offsets) ----
#define OUT_A      0
#define OUT_SC     22380544ULL
#define OUT_MUC    22730240ULL
#define OUT_SGC    22738436ULL
#define OUT_TOT    22763024ULL

typedef __attribute__((ext_vector_type(8))) short bf16x8s;
typedef __attribute__((ext_vector_type(4))) float f32x4;

static __device__ __forceinline__ unsigned short f2bf_rne(float f) {
  unsigned int u = __builtin_bit_cast(unsigned int, f);
  unsigned int r = (u + 0x7fffu + ((u >> 16) & 1u)) >> 16;
  return (unsigned short)r;
}

// monotone float -> u32 (order-preserving incl. negatives; no NaNs here)
static __device__ __forceinline__ unsigned int f2ord(float f) {
  unsigned int u = __builtin_bit_cast(unsigned int, f);
  return (u & 0x80000000u) ? ~u : (u | 0x80000000u);
}

// =====================================================================
// E[k,c] = sum_d slot_embed[k,d] * W_proj[d,c], stored as ET[c][k]
__global__ __launch_bounds__(256) void build_ET_k(const float* __restrict__ Wp,
                                                  const float* __restrict__ se,
                                                  float* __restrict__ ET) {
  int idx = blockIdx.x * 256 + threadIdx.x;
  if (idx >= C_ * KP_) return;
  int c = idx / KP_;
  int k = idx % KP_;
  float acc = 0.f;
  if (k < K_) {
    for (int d = 0; d < C_; d++) acc = fmaf(se[k * C_ + d], Wp[d * C_ + c], acc);
  }
  ET[idx] = acc;
}

// =====================================================================
// FUSED kernel, 512 threads/block:
//   blocks 0..3      : FPS (one per batch) -> anchors
//   blocks 4..1027   : semantic GEMM, 32 rows each -> Lsem into A region
//   blocks 1028..1091: build ext features
// FPS critical path design: per iteration the serial chain is
//   16-pt update/scan (issue-bound) -> 6-level u64-key butterfly (coords
//   shuffled alongside) -> 1 LDS hop + 1 barrier -> 8-entry scan.
// No dependent global loads: winner coords ride the reduction.
__global__ __launch_bounds__(512, 2) void fused_k(const float* __restrict__ s,
    const float* __restrict__ mu, const float* __restrict__ Sigma,
    const float* __restrict__ mask, const float* __restrict__ ET,
    float* __restrict__ anchors, float* __restrict__ ext,
    float* __restrict__ A) {
  const int bid = blockIdx.x;
  const int tid = threadIdx.x;

  __shared__ __align__(16) float s_lds[32][132];
  __shared__ __align__(16) float et_lds[8][KP_];
  __shared__ double redd[8][4];
  __shared__ unsigned long long redk[2][8];
  __shared__ float redx[2][8], redy[2][8], redz[2][8];

  if (bid >= 1028) {
    int idx = (bid - 1028) * 512 + tid;
    if (idx < B_ * N_) {
      float x = mu[(size_t)idx * 3 + 0];
      float y = mu[(size_t)idx * 3 + 1];
      float z = mu[(size_t)idx * 3 + 2];
      const float* S = Sigma + (size_t)idx * 9;
      float* e = ext + (size_t)idx * 16;
      e[0] = x; e[1] = y; e[2] = z;
      e[3] = x * x; e[4] = x * y; e[5] = x * z;
      e[6] = y * y; e[7] = y * z; e[8] = z * z;
      e[9] = S[0]; e[10] = S[1]; e[11] = S[2]; e[12] = S[4]; e[13] = S[5]; e[14] = S[8];
      e[15] = 1.f;
    }
    return;
  }

  if (bid >= 4) {
    const int gb = bid - 4;
    const int b = gb >> 8;
    const int n0 = (gb & 255) * 32;
    const int nt = tid >> 6;
    const int kt = tid & 63;
    {
      const float* sb = s + ((size_t)(b * N_ + n0)) * C_;
      int r = tid >> 4;
      int cb = (tid & 15) * 8;
#pragma unroll
      for (int q = 0; q < 2; q++) {
        float4 v = *(const float4*)(sb + (size_t)r * C_ + cb + q * 4);
        *(float4*)(&s_lds[r][cb + q * 4]) = v;
      }
    }
    float acc[4][12];
#pragma unroll
    for (int i = 0; i < 4; i++)
#pragma unroll
      for (int j = 0; j < 12; j++) acc[i][j] = 0.f;

    for (int cc = 0; cc < 16; cc++) {
      __syncthreads();
#pragma unroll
      for (int q = 0; q < 3; q++) {
        int fid = q * 512 + tid;
        int cl = fid / 192;
        int o4 = fid % 192;
        *(float4*)(&et_lds[cl][o4 * 4]) = *(const float4*)(ET + (size_t)(cc * 8 + cl) * KP_ + o4 * 4);
      }
      __syncthreads();
#pragma unroll
      for (int c8 = 0; c8 < 8; c8++) {
        int c = cc * 8 + c8;
        float sv0 = s_lds[nt * 4 + 0][c];
        float sv1 = s_lds[nt * 4 + 1][c];
        float sv2 = s_lds[nt * 4 + 2][c];
        float sv3 = s_lds[nt * 4 + 3][c];
#pragma unroll
        for (int j = 0; j < 12; j++) {
          float ev = et_lds[c8][kt + 64 * j];
          acc[0][j] = fmaf(sv0, ev, acc[0][j]);
          acc[1][j] = fmaf(sv1, ev, acc[1][j]);
          acc[2][j] = fmaf(sv2, ev, acc[2][j]);
          acc[3][j] = fmaf(sv3, ev, acc[3][j]);
        }
      }
    }
#pragma unroll
    for (int i = 0; i < 4; i++) {
      float* Arow = A + ((size_t)(b * N_ + n0 + nt * 4 + i)) * K_;
#pragma unroll
      for (int j = 0; j < 12; j++) {
        int k = kt + 64 * j;
        if (k < K_) Arow[k] = acc[i][j];
      }
    }
    return;
  }

  // ---------------- FPS ----------------
  const int b = bid;
  const int t = tid;
  const int wv = t >> 6;
  const float* mub = mu + (size_t)b * N_ * 3;
  const float* mkb = mask + (size_t)b * N_;
  // md encodes mask: -1 = masked (absorbing under fminf since d2 >= 0),
  // +3.4e38 = valid-uninitialized (first min gives d2-to-anchor0, matching
  // the reference min_d2 init).
  float px[16], py[16], pz[16], md[16];

  double sx = 0, sy = 0, sz = 0, sc = 0;
#pragma unroll
  for (int i = 0; i < 16; i++) {
    int p = i * 512 + t;
    px[i] = mub[p * 3 + 0];
    py[i] = mub[p * 3 + 1];
    pz[i] = mub[p * 3 + 2];
    float mk = mkb[p];
    bool valid = (mk > 0.5f);
    md[i] = valid ? 3.4e38f : -1.f;
    if (valid) { sx += px[i]; sy += py[i]; sz += pz[i]; sc += 1.0; }
  }
  for (int off = 32; off; off >>= 1) {
    sx += __shfl_xor(sx, off);
    sy += __shfl_xor(sy, off);
    sz += __shfl_xor(sz, off);
    sc += __shfl_xor(sc, off);
  }
  if ((t & 63) == 0) { redd[wv][0] = sx; redd[wv][1] = sy; redd[wv][2] = sz; redd[wv][3] = sc; }
  __syncthreads();
  if (t == 0) {
    double ax0 = 0, ay0 = 0, az0 = 0, ac = 0;
    for (int w = 0; w < 8; w++) { ax0 += redd[w][0]; ay0 += redd[w][1]; az0 += redd[w][2]; ac += redd[w][3]; }
    if (ac < 1.0) ac = 1.0;
    redx[0][0] = (float)(ax0 / ac); redy[0][0] = (float)(ay0 / ac); redz[0][0] = (float)(az0 / ac);
  }
  __syncthreads();

  float ax, ay, az;
  // -------- first anchor: argmax of masked d2-from-mean --------
  {
    float cx = redx[0][0], cy = redy[0][0], cz = redz[0][0];
    float bv = -2.f, bv2 = -2.f;
    int bi = 0, bi2 = 0;
    float bx = 0.f, by = 0.f, bz = 0.f, bx2 = 0.f, by2 = 0.f, bz2 = 0.f;
#pragma unroll
    for (int i = 0; i < 16; i++) {
      float dx = px[i] - cx, dy = py[i] - cy, dz = pz[i] - cz;
      float d2 = __fadd_rn(__fadd_rn(__fmul_rn(dx, dx), __fmul_rn(dy, dy)), __fmul_rn(dz, dz));
      float v = (md[i] < 0.f) ? -1.f : d2;
      int p = i * 512 + t;
      if (i & 1) { if (v > bv2) { bv2 = v; bi2 = p; bx2 = px[i]; by2 = py[i]; bz2 = pz[i]; } }
      else       { if (v > bv)  { bv = v;  bi = p;  bx = px[i];  by = py[i];  bz = pz[i]; } }
    }
    if (bv2 > bv || (bv2 == bv && bi2 < bi)) { bv = bv2; bi = bi2; bx = bx2; by = by2; bz = bz2; }
    unsigned long long kk = ((unsigned long long)f2ord(bv) << 32) | (unsigned int)(~bi);
    for (int off = 32; off; off >>= 1) {
      unsigned long long ok = __shfl_xor(kk, off);
      float ox = __shfl_xor(bx, off), oy = __shfl_xor(by, off), oz = __shfl_xor(bz, off);
      if (ok > kk) { kk = ok; bx = ox; by = oy; bz = oz; }
    }
    if ((t & 63) == 0) { redk[0][wv] = kk; redx[0][wv] = bx; redy[0][wv] = by; redz[0][wv] = bz; }
    __syncthreads();
    unsigned long long bk = redk[0][0];
    ax = redx[0][0]; ay = redy[0][0]; az = redz[0][0];
#pragma unroll
    for (int w = 1; w < 8; w++) {
      unsigned long long ok = redk[0][w];
      if (ok > bk) { bk = ok; ax = redx[0][w]; ay = redy[0][w]; az = redz[0][w]; }
    }
    if (t == 0) {
      float aa = ax * ax + ay * ay + az * az;
      float4 st = {ax, ay, az, aa};
      *(float4*)(anchors + ((size_t)b * KP_ + 0) * 4) = st;
    }
  }

  // -------- main loop: one barrier per iteration --------
  for (int k = 1; k < K_; k++) {
    const int par = k & 1;
    float bv = -2.f, bv2 = -2.f;
    int bi = 0, bi2 = 0;
    float bx = 0.f, by = 0.f, bz = 0.f, bx2 = 0.f, by2 = 0.f, bz2 = 0.f;
#pragma unroll
    for (int i = 0; i < 16; i++) {
      float dx = px[i] - ax, dy = py[i] - ay, dz = pz[i] - az;
      float d2 = __fadd_rn(__fadd_rn(__fmul_rn(dx, dx), __fmul_rn(dy, dy)), __fmul_rn(dz, dz));
      float m = fminf(md[i], d2);
      md[i] = m;
      int p = i * 512 + t;
      if (i & 1) { if (m > bv2) { bv2 = m; bi2 = p; bx2 = px[i]; by2 = py[i]; bz2 = pz[i]; } }
      else       { if (m > bv)  { bv = m;  bi = p;  bx = px[i];  by = py[i];  bz = pz[i]; } }
    }
    if (bv2 > bv || (bv2 == bv && bi2 < bi)) { bv = bv2; bi = bi2; bx = bx2; by = by2; bz = bz2; }
    unsigned long long kk = ((unsigned long long)f2ord(bv) << 32) | (unsigned int)(~bi);
    for (int off = 32; off; off >>= 1) {
      unsigned long long ok = __shfl_xor(kk, off);
      float ox = __shfl_xor(bx, off), oy = __shfl_xor(by, off), oz = __shfl_xor(bz, off);
      if (ok > kk) { kk = ok; bx = ox; by = oy; bz = oz; }
    }
    if ((t & 63) == 0) { redk[par][wv] = kk; redx[par][wv] = bx; redy[par][wv] = by; redz[par][wv] = bz; }
    __syncthreads();
    unsigned long long bk = redk[par][0];
    ax = redx[par][0]; ay = redy[par][0]; az = redz[par][0];
#pragma unroll
    for (int w = 1; w < 8; w++) {
      unsigned long long ok = redk[par][w];
      if (ok > bk) { bk = ok; ax = redx[par][w]; ay = redy[par][w]; az = redz[par][w]; }
    }
    if (t == 0) {
      float aa = ax * ax + ay * ay + az * az;
      float4 st = {ax, ay, az, aa};
      *(float4*)(anchors + ((size_t)b * KP_ + k) * 4) = st;
    }
  }
  for (int k = K_ + t; k < KP_; k += 512) {
    float4 z4 = {0.f, 0.f, 0.f, 0.f};
    *(float4*)(anchors + ((size_t)b * KP_ + k) * 4) = z4;
  }
}

// =====================================================================
// spatial logits + mask + softmax, in place over A (holds Lsem).
__global__ __launch_bounds__(256) void spatial_softmax_k(
    const float* __restrict__ mu, const float* __restrict__ mask,
    const float* __restrict__ anchors, const float* __restrict__ lsm_p,
    const float* __restrict__ wsem_p, const float* __restrict__ wmu_p,
    float* __restrict__ A) {
  const int bid = blockIdx.x;
  const int b = bid >> 11;
  const int n0 = (bid & 2047) * 4;
  const int tid = threadIdx.x;
  const int wv = tid >> 6;
  const int lane = tid & 63;
  __shared__ __align__(16) float anch_lds[KP_][4];
  for (int q = tid; q < KP_; q += 256)
    *(float4*)(&anch_lds[q][0]) = *(const float4*)(anchors + ((size_t)b * KP_ + q) * 4);
  __syncthreads();

  const float sg = fmaxf(expf(lsm_p[0]), 1e-4f);
  const float inv2s2 = 0.5f / (sg * sg);
  const float wsem = wsem_p[0];
  const float wmu = wmu_p[0];

  const size_t gr = (size_t)b * N_ + n0 + wv;
  const float* mp = mu + gr * 3;
  float x = mp[0], y = mp[1], z = mp[2];
  float mq = x * x + y * y + z * z;
  float mk = mask[gr];
  float* Arow = A + gr * K_;

  float v[11];
  float m = -3e38f;
#pragma unroll
  for (int j = 0; j < 11; j++) {
    int k = lane + 64 * j;
    if (k < K_) {
      float lsem = Arow[k];
      float4 a4 = *(const float4*)(&anch_lds[k][0]);
      float tdot = x * a4.x + y * a4.y + z * a4.z;
      float d2 = mq - 2.f * tdot + a4.w;
      float l = wsem * lsem - wmu * d2 * inv2s2;
      if (mk < 0.5f) l = -1e9f;
      v[j] = l;
    } else v[j] = -1e30f;
    m = fmaxf(m, v[j]);
  }
  for (int off = 32; off; off >>= 1) m = fmaxf(m, __shfl_xor(m, off));
  float sum = 0.f;
#pragma unroll
  for (int j = 0; j < 11; j++) { float e = expf(v[j] - m); v[j] = e; sum += e; }
  for (int off = 32; off; off >>= 1) sum += __shfl_xor(sum, off);
  float r = mk / sum;
#pragma unroll
  for (int j = 0; j < 11; j++) {
    int k = lane + 64 * j;
    if (k < K_) Arow[k] = v[j] * r;
  }
}

// =====================================================================
// Transpose A fp32 [b][n][683] -> At bf16 [b][768][8192] (pad rows zero)
__global__ __launch_bounds__(256) void transpose_at_k(const float* __restrict__ A,
    unsigned short* __restrict__ At) {
  const int bid = blockIdx.x;          // b(4) * ktile(12) * ntile(128)
  const int ntile = bid % 128;
  const int rem = bid / 128;
  const int kt = rem % 12;
  const int b = rem / 12;
  const int k0 = kt * 64, n0 = ntile * 64;
  const int tid = threadIdx.x;
  __shared__ __align__(16) unsigned short T[64][72];

  {
    const int n_loc = tid >> 4;        // 0..15
    const int k4 = (tid & 15) * 4;
#pragma unroll
    for (int nn = 0; nn < 4; nn++) {
      int n = n_loc + 16 * nn;
      const float* ar = A + ((size_t)(b * N_ + n0 + n)) * K_;
#pragma unroll
      for (int q = 0; q < 4; q++) {
        int kk = k0 + k4 + q;
        float f = (kk < K_) ? ar[kk] : 0.f;
        T[k4 + q][n] = f2bf_rne(f);
      }
    }
  }
  __syncthreads();
  {
    const int k_loc = tid >> 2;        // 0..63
    const int c = tid & 3;             // 16-ushort chunk
    uint4 v0 = *(const uint4*)(&T[k_loc][c * 16]);
    uint4 v1 = *(const uint4*)(&T[k_loc][c * 16 + 8]);
    unsigned short* dst = At + ((size_t)(b * KP_ + k0 + k_loc)) * N_ + n0 + c * 16;
    *(uint4*)dst = v0;
    *(uint4*)(dst + 8) = v1;
  }
}

// =====================================================================
// MFMA gram + fused collapse-loss tile partial.
// 84 blocks = 4 b x 21 symmetric 128x128 tiles; full N reduction per block.
__global__ __launch_bounds__(256) void gram_mfma_k(const unsigned short* __restrict__ At,
    const float* __restrict__ norm_ws, float* __restrict__ lossp) {
  const int bid = blockIdx.x;
  const int b = bid / 21;
  int p = bid % 21;
  int tk = 0, tl = 0;
  { int pp = p; for (int r0 = 0; r0 < 6; r0++) { int cnt = 6 - r0; if (pp < cnt) { tk = r0; tl = r0 + pp; break; } pp -= cnt; } }
  const int k0 = tk * 128, l0 = tl * 128;
  const int tid = threadIdx.x;
  const int l = tid & 63;
  const int w = tid >> 6;
  const int wr = w >> 1, wc = w & 1;

  __shared__ __align__(16) unsigned short Ak_lds[128 * 72];
  __shared__ __align__(16) unsigned short Al_lds[128 * 72];
  __shared__ float nk_s[128], nl_s[128], red_s[4];

  if (tid < 128) {
    int kk = k0 + tid;
    nk_s[tid] = (kk < K_) ? fmaxf(norm_ws[b * KT_ + kk], 1e-8f) : 1.f;
  } else {
    int ll2 = l0 + tid - 128;
    nl_s[tid - 128] = (ll2 < K_) ? fmaxf(norm_ws[b * KT_ + ll2], 1e-8f) : 1.f;
  }

  f32x4 acc[4][4];
#pragma unroll
  for (int i = 0; i < 4; i++)
#pragma unroll
    for (int j = 0; j < 4; j++) acc[i][j] = (f32x4){0.f, 0.f, 0.f, 0.f};

  const unsigned short* gk = At + ((size_t)(b * KP_ + k0)) * N_;
  const unsigned short* gl = At + ((size_t)(b * KP_ + l0)) * N_;

  for (int ch = 0; ch < 128; ch++) {
    const int n0 = ch * 64;
    __syncthreads();
#pragma unroll
    for (int q = 0; q < 4; q++) {
      int chunk = tid + 256 * q;
      int row = chunk >> 3, slot = chunk & 7;
      uint4 v = *(const uint4*)(gk + (size_t)row * N_ + n0 + slot * 8);
      *(uint4*)(Ak_lds + row * 72 + slot * 8) = v;
      uint4 v2 = *(const uint4*)(gl + (size_t)row * N_ + n0 + slot * 8);
      *(uint4*)(Al_lds + row * 72 + slot * 8) = v2;
    }
    __syncthreads();
#pragma unroll
    for (int ks = 0; ks < 2; ks++) {
      const int noff = (l >> 4) * 8 + ks * 32;
      bf16x8s af[4], bfr[4];
#pragma unroll
      for (int f = 0; f < 4; f++) {
        af[f]  = *(const bf16x8s*)(Ak_lds + (wr * 64 + f * 16 + (l & 15)) * 72 + noff);
        bfr[f] = *(const bf16x8s*)(Al_lds + (wc * 64 + f * 16 + (l & 15)) * 72 + noff);
      }
#pragma unroll
      for (int i = 0; i < 4; i++)
#pragma unroll
        for (int j = 0; j < 4; j++)
          acc[i][j] = __builtin_amdgcn_mfma_f32_16x16x32_bf16(af[i], bfr[j], acc[i][j], 0, 0, 0);
    }
  }

  // epilogue: loss partial for this tile
  float local = 0.f;
  const float wgt = (tk == tl) ? 1.f : 2.f;
#pragma unroll
  for (int i = 0; i < 4; i++) {
#pragma unroll
    for (int j = 0; j < 4; j++) {
#pragma unroll
      for (int r = 0; r < 4; r++) {
        int ki = wr * 64 + i * 16 + (l >> 4) * 4 + r;   // local row
        int li = wc * 64 + j * 16 + (l & 15);           // local col
        int gkk = k0 + ki, gll = l0 + li;
        if (gkk < K_ && gll < K_ && gkk != gll) {
          float g = acc[i][j][r];
          float x = g / (nk_s[ki] * nl_s[li]);
          local = fmaf(wgt * x, x, local);
        }
      }
    }
  }
  for (int off = 32; off; off >>= 1) local += __shfl_xor(local, off);
  if ((tid & 63) == 0) red_s[w] = local;
  __syncthreads();
  if (tid == 0) lossp[bid] = red_s[0] + red_s[1] + red_s[2] + red_s[3];
}

// =====================================================================
// GEMM2: moments = A^T x F, F = [s(128) | ext(16) | pad(16)], plus sum(A^2).
__global__ __launch_bounds__(256) void gemm2_k(const float* __restrict__ A,
    const float* __restrict__ s, const float* __restrict__ ext,
    float* __restrict__ part) {
  const int bid = blockIdx.x;
  const int np = bid / 44;
  const int rem = bid % 44;
  const int b = rem / 11;
  const int k0 = (rem % 11) * 64;
  const int n0 = np * 1024;
  const int tid = threadIdx.x;
  const int kt = tid & 15;
  const int ft = tid >> 4;
  __shared__ __align__(16) float A_lds[32][64];
  __shared__ __align__(16) float F_lds[32][160];
  float acc[4][10];
#pragma unroll
  for (int c = 0; c < 4; c++)
#pragma unroll
    for (int f = 0; f < 10; f++) acc[c][f] = 0.f;
  float asq[4] = {0.f, 0.f, 0.f, 0.f};

  for (int ch = 0; ch < 32; ch++) {
    int nb = n0 + ch * 32;
    __syncthreads();
#pragma unroll
    for (int p = 0; p < 8; p++) {
      int q = tid + 256 * p; int r = q >> 6; int c = q & 63; int k = k0 + c;
      A_lds[r][c] = (k < K_) ? A[((size_t)(b * N_ + nb + r)) * K_ + k] : 0.f;
    }
#pragma unroll
    for (int p = 0; p < 16; p++) {
      int q = tid + 256 * p; int r = q >> 7; int c = q & 127;
      F_lds[r][c] = s[((size_t)(b * N_ + nb + r)) * C_ + c];
    }
#pragma unroll
    for (int p = 0; p < 2; p++) {
      int q = tid + 256 * p; int r = q >> 4; int e = q & 15;
      F_lds[r][128 + e] = ext[((size_t)(b * N_ + nb + r)) * 16 + e];
      F_lds[r][144 + e] = 0.f;
    }
    __syncthreads();
#pragma unroll
    for (int i = 0; i < 32; i++) {
      float a0 = A_lds[i][kt * 4 + 0];
      float a1 = A_lds[i][kt * 4 + 1];
      float a2 = A_lds[i][kt * 4 + 2];
      float a3 = A_lds[i][kt * 4 + 3];
      if (ft == 0) {
        asq[0] = fmaf(a0, a0, asq[0]); asq[1] = fmaf(a1, a1, asq[1]);
        asq[2] = fmaf(a2, a2, asq[2]); asq[3] = fmaf(a3, a3, asq[3]);
      }
#pragma unroll
      for (int f = 0; f < 10; f++) {
        float fv = F_lds[i][ft * 10 + f];
        acc[0][f] = fmaf(a0, fv, acc[0][f]);
        acc[1][f] = fmaf(a1, fv, acc[1][f]);
        acc[2][f] = fmaf(a2, fv, acc[2][f]);
        acc[3][f] = fmaf(a3, fv, acc[3][f]);
      }
    }
  }
#pragma unroll
  for (int c = 0; c < 4; c++) {
    size_t base = ((size_t)((np * 4 + b) * KT_ + k0 + kt * 4 + c)) * 168;
#pragma unroll
    for (int f = 0; f < 10; f++) part[base + ft * 10 + f] = acc[c][f];
    if (ft == 0) part[base + 160] = asq[c];
  }
}

// =====================================================================
// Postprocess: one wave per (b,k): s_c, mu_c, Sigma_c, sumA, norms.
__global__ __launch_bounds__(256) void postproc_k(const float* __restrict__ part,
    float* __restrict__ out, float* __restrict__ sumA_ws, float* __restrict__ norm_ws) {
  const int gw = blockIdx.x * 4 + (threadIdx.x >> 6);
  const int lane = threadIdx.x & 63;
  const int b = gw / K_;
  const int k = gw % K_;
  float v0 = 0.f, v1 = 0.f, v2 = 0.f, v3 = 0.f;
  for (int np = 0; np < 8; np++) {
    const float* r = part + ((size_t)((np * 4 + b) * KT_ + k)) * 168;
    v0 += r[lane];
    v1 += r[64 + lane];
    if (lane < 16) v2 += r[128 + lane];
    if (lane == 0) v3 += r[160];
  }
  float sumA = __shfl(v2, 15);
  float asq = __shfl(v3, 0);
  float denom = fmaxf(sumA, 1e-8f);
  float inv = 1.f / denom;
  out[OUT_SC + ((size_t)(b * K_ + k)) * C_ + lane] = v0 * inv;
  out[OUT_SC + ((size_t)(b * K_ + k)) * C_ + 64 + lane] = v1 * inv;
  float m0 = __shfl(v2, 0) * inv;
  float m1 = __shfl(v2, 1) * inv;
  float m2 = __shfl(v2, 2) * inv;
  if (lane < 3) out[OUT_MUC + ((size_t)(b * K_ + k)) * 3 + lane] = (lane == 0) ? m0 : ((lane == 1) ? m1 : m2);
  float W = sumA * inv;
  float fac = 2.f - W;
  float M2s[6], Sgs[6];
#pragma unroll
  for (int j = 0; j < 6; j++) { M2s[j] = __shfl(v2, 3 + j); Sgs[j] = __shfl(v2, 9 + j); }
  if (lane < 9) {
    int d = lane / 3, e = lane % 3;
    int lo = min(d, e), hi = max(d, e);
    int j = hi + 2 * lo - ((lo * (lo - 1)) >> 1);
    float mud = (d == 0) ? m0 : ((d == 1) ? m1 : m2);
    float mue = (e == 0) ? m0 : ((e == 1) ? m1 : m2);
    float M2j = (j == 0) ? M2s[0] : (j == 1) ? M2s[1] : (j == 2) ? M2s[2] : (j == 3) ? M2s[3] : (j == 4) ? M2s[4] : M2s[5];
    float Sgj = (j == 0) ? Sgs[0] : (j == 1) ? Sgs[1] : (j == 2) ? Sgs[2] : (j == 3) ? Sgs[3] : (j == 4) ? Sgs[4] : Sgs[5];
    float val = (Sgj + M2j) * inv - mud * mue * fac;
    if (d == e) val += 1e-6f;
    out[OUT_SGC + ((size_t)(b * K_ + k)) * 9 + lane] = val;
  }
  if (lane == 0) { sumA_ws[b * KT_ + k] = sumA; norm_ws[b * KT_ + k] = sqrtf(asq); }
}

// =====================================================================
// OLD fp32 gram path (fallback if ws too small for At)
__device__ __forceinline__ int swz(int f) { return f ^ (((f >> 5) & 3) << 3); }

__global__ __launch_bounds__(256) void gram_k(const float* __restrict__ A,
                                              float* __restrict__ Gpart) {
  const int bid = blockIdx.x;
  const int np = bid & 1;
  int q = bid >> 1;
  const int b = q / 21;
  int p = q % 21;
  int tk = 0, tl = 0;
  { int pp = p; for (int r0 = 0; r0 < 6; r0++) { int cnt = 6 - r0; if (pp < cnt) { tk = r0; tl = r0 + pp; break; } pp -= cnt; } }
  const int k0 = tk * 128, l0 = tl * 128;
  const int n0 = np * 4096;
  const int tid = threadIdx.x;
  const int ktid = tid & 15, ltid = tid >> 4;
  const bool diag = (tk == tl);
  __shared__ __align__(16) float Ak[32][128];
  __shared__ __align__(16) float Al[32][128];
  float acc[8][8];
#pragma unroll
  for (int i = 0; i < 8; i++)
#pragma unroll
    for (int j = 0; j < 8; j++) acc[i][j] = 0.f;

  const int kb = swz(ktid * 8);
  const int lb = swz(ltid * 8);
  for (int ch = 0; ch < 128; ch++) {
    int nb = n0 + ch * 32;
    __syncthreads();
#pragma unroll
    for (int pq = 0; pq < 16; pq++) {
      int qq = tid + 256 * pq; int r = qq >> 7; int c = qq & 127;
      int kk = k0 + c;
      Ak[r][swz(c)] = (kk < K_) ? A[((size_t)(b * N_ + nb + r)) * K_ + kk] : 0.f;
      if (!diag) {
        int ll = l0 + c;
        Al[r][swz(c)] = (ll < K_) ? A[((size_t)(b * N_ + nb + r)) * K_ + ll] : 0.f;
      }
    }
    __syncthreads();
    const float (*Alp)[128] = diag ? Ak : Al;
#pragma unroll
    for (int i = 0; i < 32; i++) {
      float4 ka = *(const float4*)(&Ak[i][kb]);
      float4 kb4 = *(const float4*)(&Ak[i][kb + 4]);
      float4 la = *(const float4*)(&Alp[i][lb]);
      float4 lb4 = *(const float4*)(&Alp[i][lb + 4]);
      float av[8] = {ka.x, ka.y, ka.z, ka.w, kb4.x, kb4.y, kb4.z, kb4.w};
      float lv[8] = {la.x, la.y, la.z, la.w, lb4.x, lb4.y, lb4.z, lb4.w};
#pragma unroll
      for (int ii = 0; ii < 8; ii++)
#pragma unroll
        for (int jj = 0; jj < 8; jj++)
          acc[ii][jj] = fmaf(av[ii], lv[jj], acc[ii][jj]);
    }
  }
#pragma unroll
  for (int ii = 0; ii < 8; ii++) {
    int kk = k0 + ktid * 8 + ii;
    float* gp = Gpart + ((size_t)((np * 4 + b) * KP_ + kk)) * KP_ + l0 + ltid * 8;
#pragma unroll
    for (int jj = 0; jj < 8; jj++) gp[jj] = acc[ii][jj];
  }
}

__global__ __launch_bounds__(256) void loss_part_k(const float* __restrict__ Gpart,
    const float* __restrict__ norm_ws, float* __restrict__ lossp) {
  const long long total = (long long)B_ * 21 * 16384;
  float local = 0.f;
  for (long long idx = (long long)blockIdx.x * 256 + threadIdx.x; idx < total; idx += (long long)512 * 256) {
    int e = (int)(idx & 16383);
    int rest = (int)(idx >> 14);
    int p = rest % 21;
    int b = rest / 21;
    int tk = 0, tl = 0;
    { int pp = p; for (int r0 = 0; r0 < 6; r0++) { int cnt = 6 - r0; if (pp < cnt) { tk = r0; tl = r0 + pp; break; } pp -= cnt; } }
    int i = e >> 7, j = e & 127;
    int k = tk * 128 + i, l = tl * 128 + j;
    if (k < K_ && l < K_ && k != l) {
      size_t i0 = ((size_t)((0 * 4 + b) * KP_ + k)) * KP_ + l;
      size_t i1 = ((size_t)((1 * 4 + b) * KP_ + k)) * KP_ + l;
      float g = Gpart[i0] + Gpart[i1];
      float nk = fmaxf(norm_ws[b * KT_ + k], 1e-8f);
      float nl2 = fmaxf(norm_ws[b * KT_ + l], 1e-8f);
      float x = g / (nk * nl2);
      float wgt = (tk == tl) ? 1.f : 2.f;
      local = fmaf(wgt * x, x, local);
    }
  }
  __shared__ float red[4];
  for (int off = 32; off; off >>= 1) local += __shfl_xor(local, off);
  if ((threadIdx.x & 63) == 0) red[threadIdx.x >> 6] = local;
  __syncthreads();
  if (threadIdx.x == 0) lossp[blockIdx.x] = red[0] + red[1] + red[2] + red[3];
}

__global__ __launch_bounds__(256) void final_k(const float* __restrict__ sumA_ws,
    const float* __restrict__ lossp, float* __restrict__ out) {
  const int lane = threadIdx.x & 63;
  const int wv = threadIdx.x >> 6;
  __shared__ float occ_s[4];
  __shared__ float col_s[4];
  float sb = 0.f;
  for (int k = lane; k < K_; k += 64) sb += sumA_ws[wv * KT_ + k];
  for (int off = 32; off; off >>= 1) sb += __shfl_xor(sb, off);
  float Sb = fmaxf(sb, 1e-8f);
  float lo = 0.f;
  const float tgt = 1.f / (float)K_;
  for (int k = lane; k < K_; k += 64) {
    float o = sumA_ws[wv * KT_ + k] / Sb - tgt;
    lo = fmaf(o, o, lo);
  }
  for (int off = 32; off; off >>= 1) lo += __shfl_xor(lo, off);
  if (lane == 0) occ_s[wv] = lo;
  float c = lossp[threadIdx.x] + lossp[threadIdx.x + 256];
  for (int off = 32; off; off >>= 1) c += __shfl_xor(c, off);
  if (lane == 0) col_s[wv] = c;
  __syncthreads();
  if (threadIdx.x == 0) {
    float loss_occ = (occ_s[0] + occ_s[1] + occ_s[2] + occ_s[3]) / (float)(B_ * K_);
    float coll = (col_s[0] + col_s[1] + col_s[2] + col_s[3]) / ((float)B_ * K_ * K_);
    out[OUT_TOT] = loss_occ + 0.1f * coll;
  }
}

// final for the MFMA path: 84 tile partials
__global__ __launch_bounds__(256) void final2_k(const float* __restrict__ sumA_ws,
    const float* __restrict__ lossp, float* __restrict__ out) {
  const int lane = threadIdx.x & 63;
  const int wv = threadIdx.x >> 6;
  __shared__ float occ_s[4];
  __shared__ float col_s[4];
  float sb = 0.f;
  for (int k = lane; k < K_; k += 64) sb += sumA_ws[wv * KT_ + k];
  for (int off = 32; off; off >>= 1) sb += __shfl_xor(sb, off);
  float Sb = fmaxf(sb, 1e-8f);
  float lo = 0.f;
  const float tgt = 1.f / (float)K_;
  for (int k = lane; k < K_; k += 64) {
    float o = sumA_ws[wv * KT_ + k] / Sb - tgt;
    lo = fmaf(o, o, lo);
  }
  for (int off = 32; off; off >>= 1) lo += __shfl_xor(lo, off);
  if (lane == 0) occ_s[wv] = lo;
  float c = 0.f;
  for (int i = threadIdx.x; i < 84; i += 256) c += lossp[i];
  for (int off = 32; off; off >>= 1) c += __shfl_xor(c, off);
  if (lane == 0) col_s[wv] = c;
  __syncthreads();
  if (threadIdx.x == 0) {
    float loss_occ = (occ_s[0] + occ_s[1] + occ_s[2] + occ_s[3]) / (float)(B_ * K_);
    float coll = (col_s[0] + col_s[1] + col_s[2] + col_s[3]) / ((float)B_ * K_ * K_);
    out[OUT_TOT] = loss_occ + 0.1f * coll;
  }
}

// =====================================================================
extern "C" void kernel_launch(void* const* d_in, const int* in_sizes, int n_in,
                              void* d_out, int out_size, void* d_ws, size_t ws_size,
                              hipStream_t stream) {
  const float* s = (const float*)d_in[0];
  const float* mu = (const float*)d_in[1];
  const float* Sigma = (const float*)d_in[2];
  const float* mask = (const float*)d_in[3];
  const float* Wp = (const float*)d_in[4];
  const float* se = (const float*)d_in[5];
  const float* lsm = (const float*)d_in[6];
  const float* wsem = (const float*)d_in[7];
  const float* wmu = (const float*)d_in[8];
  float* out = (float*)d_out;
  float* ws = (float*)d_ws;

  float* ET = ws + WS_ET;
  float* anch = ws + WS_ANCH;
  float* ext = ws + WS_EXT;
  float* part = ws + WS_PART;
  float* sumA = ws + WS_SUMA;
  float* nrm = ws + WS_NORM;

  hipLaunchKernelGGL(build_ET_k, dim3(384), dim3(256), 0, stream, Wp, se, ET);
  hipLaunchKernelGGL(fused_k, dim3(1092), dim3(512), 0, stream, s, mu, Sigma, mask, ET, anch, ext, out);
  hipLaunchKernelGGL(spatial_softmax_k, dim3(8192), dim3(256), 0, stream, mu, mask, anch, lsm, wsem, wmu, out);
  hipLaunchKernelGGL(gemm2_k, dim3(352), dim3(256), 0, stream, out, s, ext, part);
  hipLaunchKernelGGL(postproc_k, dim3(683), dim3(256), 0, stream, part, out, sumA, nrm);

  const bool use_mfma = ws_size >= (size_t)WS_NEW_END * 4;
  if (use_mfma) {
    float* lossp2 = ws + WS_LOSSP2;
    unsigned short* At = (unsigned short*)(ws + WS_AT);
    hipLaunchKernelGGL(transpose_at_k, dim3(4 * 12 * 128), dim3(256), 0, stream, out, At);
    hipLaunchKernelGGL(gram_mfma_k, dim3(84), dim3(256), 0, stream, At, nrm, lossp2);
    hipLaunchKernelGGL(final2_k, dim3(1), dim3(256), 0, stream, sumA, lossp2, out);
  } else {
    float* Gpart = ws + WS_GPART;
    float* lossp = ws + WS_LOSSP;
    hipLaunchKernelGGL(gram_k, dim3(168), dim3(256), 0, stream, out, Gpart);
    hipLaunchKernelGGL(loss_part_k, dim3(512), dim3(256), 0, stream, Gpart, nrm, lossp);
    hipLaunchKernelGGL(final_k, dim3(1), dim3(256), 0, stream, sumA, lossp, out);
  }
}

// Round 7
// 1406.579 us; speedup vs baseline: 1.3199x; 1.2360x over previous
//
#include <hip/hip_runtime.h>
#include <hip/hip_bf16.h>
#include <math.h>

#define B_ 4
#define N_ 8192
#define C_ 128
#define K_ 683
#define KP_ 768
#define KT_ 704   // 11*64 padded K for moments

// ---- workspace layout (float offsets) ----
#define WS_ET      0          // 128*768        = 98304
#define WS_ANCH    98304      // 4*768*4        = 12288
#define WS_EXT     110592     // 4*8192*16      = 524288
#define WS_PART    634880     // 8*4*704*168    = 3784704
#define WS_SUMA    4419584    // 4*704          = 2816
#define WS_NORM    4422400    // 4*704          = 2816
// -- new (MFMA) path --
#define WS_LOSSP2  4425216    // 128 floats (84 tile partials)
#define WS_AT      4425344    // bf16 At[4][768][8192] = 12582912 floats worth
#define WS_NEW_END 17008256   // floats -> 68,033,024 bytes
// -- old (fallback) path --
#define WS_GPART   4425216    // 2*4*768*768    = 4718592
#define WS_LOSSP   9143808    // 512

// ---- output layout (float offsets) ----
#define OUT_A      0
#define OUT_SC     22380544ULL
#define OUT_MUC    22730240ULL
#define OUT_SGC    22738436ULL
#define OUT_TOT    22763024ULL

typedef __attribute__((ext_vector_type(8))) short bf16x8s;
typedef __attribute__((ext_vector_type(4))) float f32x4;

static __device__ __forceinline__ unsigned short f2bf_rne(float f) {
  unsigned int u = __builtin_bit_cast(unsigned int, f);
  unsigned int r = (u + 0x7fffu + ((u >> 16) & 1u)) >> 16;
  return (unsigned short)r;
}

// monotone float -> u32 (order-preserving incl. negatives; no NaNs here)
static __device__ __forceinline__ unsigned int f2ord(float f) {
  unsigned int u = __builtin_bit_cast(unsigned int, f);
  return (u & 0x80000000u) ? ~u : (u | 0x80000000u);
}

static __device__ __forceinline__ unsigned long long umax64(unsigned long long a,
                                                           unsigned long long b) {
  return a > b ? a : b;
}

// =====================================================================
// E[k,c] = sum_d slot_embed[k,d] * W_proj[d,c], stored as ET[c][k]
__global__ __launch_bounds__(256) void build_ET_k(const float* __restrict__ Wp,
                                                  const float* __restrict__ se,
                                                  float* __restrict__ ET) {
  int idx = blockIdx.x * 256 + threadIdx.x;
  if (idx >= C_ * KP_) return;
  int c = idx / KP_;
  int k = idx % KP_;
  float acc = 0.f;
  if (k < K_) {
    for (int d = 0; d < C_; d++) acc = fmaf(se[k * C_ + d], Wp[d * C_ + c], acc);
  }
  ET[idx] = acc;
}

// =====================================================================
// FUSED kernel, 512 threads/block:
//   blocks 0..3      : FPS (one per batch) -> anchors
//   blocks 4..1027   : semantic GEMM, 32 rows each -> Lsem into A region
//   blocks 1028..1091: build ext features
// FPS design (per-iteration serial chain, one barrier/iter):
//   16-pt (val,idx) scan [12 VALU ops/pt, no coord tracking]
//   -> pack u64 key once -> 6-level u64 butterfly (2 bpermute/level)
//   -> lane0 ds_write_b64 -> barrier -> all threads read 8 keys + register
//   tree -> winner coords via broadcast ds_read from LDS-staged mu.
// LDS-staged mu (96KB) makes the fps block sole occupant of its CU.
__global__ __launch_bounds__(512, 1) void fused_k(const float* __restrict__ s,
    const float* __restrict__ mu, const float* __restrict__ Sigma,
    const float* __restrict__ mask, const float* __restrict__ ET,
    float* __restrict__ anchors, float* __restrict__ ext,
    float* __restrict__ A) {
  const int bid = blockIdx.x;
  const int tid = threadIdx.x;

  __shared__ __align__(16) float s_lds[32][132];
  __shared__ __align__(16) float et_lds[8][KP_];
  __shared__ __align__(16) float muL[N_ * 3];        // 96 KB (fps only)
  __shared__ double redd[8][4];
  __shared__ unsigned long long redk[2][8];
  __shared__ float an_s[4];

  if (bid >= 1028) {
    int idx = (bid - 1028) * 512 + tid;
    if (idx < B_ * N_) {
      float x = mu[(size_t)idx * 3 + 0];
      float y = mu[(size_t)idx * 3 + 1];
      float z = mu[(size_t)idx * 3 + 2];
      const float* S = Sigma + (size_t)idx * 9;
      float* e = ext + (size_t)idx * 16;
      e[0] = x; e[1] = y; e[2] = z;
      e[3] = x * x; e[4] = x * y; e[5] = x * z;
      e[6] = y * y; e[7] = y * z; e[8] = z * z;
      e[9] = S[0]; e[10] = S[1]; e[11] = S[2]; e[12] = S[4]; e[13] = S[5]; e[14] = S[8];
      e[15] = 1.f;
    }
    return;
  }

  if (bid >= 4) {
    const int gb = bid - 4;
    const int b = gb >> 8;
    const int n0 = (gb & 255) * 32;
    const int nt = tid >> 6;
    const int kt = tid & 63;
    {
      const float* sb = s + ((size_t)(b * N_ + n0)) * C_;
      int r = tid >> 4;
      int cb = (tid & 15) * 8;
#pragma unroll
      for (int q = 0; q < 2; q++) {
        float4 v = *(const float4*)(sb + (size_t)r * C_ + cb + q * 4);
        *(float4*)(&s_lds[r][cb + q * 4]) = v;
      }
    }
    float acc[4][12];
#pragma unroll
    for (int i = 0; i < 4; i++)
#pragma unroll
      for (int j = 0; j < 12; j++) acc[i][j] = 0.f;

    for (int cc = 0; cc < 16; cc++) {
      __syncthreads();
#pragma unroll
      for (int q = 0; q < 3; q++) {
        int fid = q * 512 + tid;
        int cl = fid / 192;
        int o4 = fid % 192;
        *(float4*)(&et_lds[cl][o4 * 4]) = *(const float4*)(ET + (size_t)(cc * 8 + cl) * KP_ + o4 * 4);
      }
      __syncthreads();
#pragma unroll
      for (int c8 = 0; c8 < 8; c8++) {
        int c = cc * 8 + c8;
        float sv0 = s_lds[nt * 4 + 0][c];
        float sv1 = s_lds[nt * 4 + 1][c];
        float sv2 = s_lds[nt * 4 + 2][c];
        float sv3 = s_lds[nt * 4 + 3][c];
#pragma unroll
        for (int j = 0; j < 12; j++) {
          float ev = et_lds[c8][kt + 64 * j];
          acc[0][j] = fmaf(sv0, ev, acc[0][j]);
          acc[1][j] = fmaf(sv1, ev, acc[1][j]);
          acc[2][j] = fmaf(sv2, ev, acc[2][j]);
          acc[3][j] = fmaf(sv3, ev, acc[3][j]);
        }
      }
    }
#pragma unroll
    for (int i = 0; i < 4; i++) {
      float* Arow = A + ((size_t)(b * N_ + n0 + nt * 4 + i)) * K_;
#pragma unroll
      for (int j = 0; j < 12; j++) {
        int k = kt + 64 * j;
        if (k < K_) Arow[k] = acc[i][j];
      }
    }
    return;
  }

  // ---------------- FPS ----------------
  const int b = bid;
  const int t = tid;
  const int wv = t >> 6;
  const float* mub = mu + (size_t)b * N_ * 3;
  const float* mkb = mask + (size_t)b * N_;
  // md encodes mask: -1 = masked (absorbing under fminf since d2 >= 0),
  // +3.4e38 = valid-uninitialized (first min gives d2-to-anchor0, matching
  // the reference min_d2 init).
  float px[16], py[16], pz[16], md[16];

  double sx = 0, sy = 0, sz = 0, sc = 0;
#pragma unroll
  for (int i = 0; i < 16; i++) {
    int p = i * 512 + t;
    px[i] = mub[p * 3 + 0];
    py[i] = mub[p * 3 + 1];
    pz[i] = mub[p * 3 + 2];
    muL[p * 3 + 0] = px[i];
    muL[p * 3 + 1] = py[i];
    muL[p * 3 + 2] = pz[i];
    float mk = mkb[p];
    bool valid = (mk > 0.5f);
    md[i] = valid ? 3.4e38f : -1.f;
    if (valid) { sx += px[i]; sy += py[i]; sz += pz[i]; sc += 1.0; }
  }
  for (int off = 32; off; off >>= 1) {
    sx += __shfl_xor(sx, off);
    sy += __shfl_xor(sy, off);
    sz += __shfl_xor(sz, off);
    sc += __shfl_xor(sc, off);
  }
  if ((t & 63) == 0) { redd[wv][0] = sx; redd[wv][1] = sy; redd[wv][2] = sz; redd[wv][3] = sc; }
  __syncthreads();
  if (t == 0) {
    double ax0 = 0, ay0 = 0, az0 = 0, ac = 0;
    for (int w = 0; w < 8; w++) { ax0 += redd[w][0]; ay0 += redd[w][1]; az0 += redd[w][2]; ac += redd[w][3]; }
    if (ac < 1.0) ac = 1.0;
    an_s[0] = (float)(ax0 / ac); an_s[1] = (float)(ay0 / ac); an_s[2] = (float)(az0 / ac);
  }
  __syncthreads();

  float ax, ay, az;
  // -------- first anchor: argmax of masked d2-from-mean --------
  {
    float cx = an_s[0], cy = an_s[1], cz = an_s[2];
    float bv = -2.f, bv2 = -2.f;
    int bi = 0, bi2 = 0;
#pragma unroll
    for (int i = 0; i < 16; i++) {
      float dx = px[i] - cx, dy = py[i] - cy, dz = pz[i] - cz;
      float d2 = __fadd_rn(__fadd_rn(__fmul_rn(dx, dx), __fmul_rn(dy, dy)), __fmul_rn(dz, dz));
      float v = (md[i] < 0.f) ? -1.f : d2;
      int p = i * 512 + t;
      if (i & 1) { if (v > bv2) { bv2 = v; bi2 = p; } }
      else       { if (v > bv)  { bv = v;  bi = p; } }
    }
    if (bv2 > bv || (bv2 == bv && bi2 < bi)) { bv = bv2; bi = bi2; }
    unsigned long long kk = ((unsigned long long)f2ord(bv) << 32) | (unsigned int)(~bi);
    for (int off = 32; off; off >>= 1) {
      unsigned long long ok = __shfl_xor(kk, off);
      if (ok > kk) kk = ok;
    }
    if ((t & 63) == 0) redk[0][wv] = kk;
    __syncthreads();
    unsigned long long a0 = redk[0][0], a1 = redk[0][1], a2 = redk[0][2], a3 = redk[0][3];
    unsigned long long a4 = redk[0][4], a5 = redk[0][5], a6 = redk[0][6], a7 = redk[0][7];
    unsigned long long bk = umax64(umax64(umax64(a0, a1), umax64(a2, a3)),
                                  umax64(umax64(a4, a5), umax64(a6, a7)));
    int besti = (int)(~(unsigned int)bk);
    ax = muL[besti * 3 + 0]; ay = muL[besti * 3 + 1]; az = muL[besti * 3 + 2];
    if (t == 0) {
      float aa = ax * ax + ay * ay + az * az;
      float4 st = {ax, ay, az, aa};
      *(float4*)(anchors + ((size_t)b * KP_ + 0) * 4) = st;
    }
  }

  // -------- main loop: one barrier per iteration --------
  for (int k = 1; k < K_; k++) {
    const int par = k & 1;
    float bv = -2.f, bv2 = -2.f;
    int bi = 0, bi2 = 0;
#pragma unroll
    for (int i = 0; i < 16; i++) {
      float dx = px[i] - ax, dy = py[i] - ay, dz = pz[i] - az;
      float d2 = __fadd_rn(__fadd_rn(__fmul_rn(dx, dx), __fmul_rn(dy, dy)), __fmul_rn(dz, dz));
      float m = fminf(md[i], d2);
      md[i] = m;
      int p = i * 512 + t;
      if (i & 1) { if (m > bv2) { bv2 = m; bi2 = p; } }
      else       { if (m > bv)  { bv = m;  bi = p; } }
    }
    if (bv2 > bv || (bv2 == bv && bi2 < bi)) { bv = bv2; bi = bi2; }
    unsigned long long kk = ((unsigned long long)f2ord(bv) << 32) | (unsigned int)(~bi);
    for (int off = 32; off; off >>= 1) {
      unsigned long long ok = __shfl_xor(kk, off);
      if (ok > kk) kk = ok;
    }
    if ((t & 63) == 0) redk[par][wv] = kk;
    __syncthreads();
    unsigned long long a0 = redk[par][0], a1 = redk[par][1], a2 = redk[par][2], a3 = redk[par][3];
    unsigned long long a4 = redk[par][4], a5 = redk[par][5], a6 = redk[par][6], a7 = redk[par][7];
    unsigned long long bk = umax64(umax64(umax64(a0, a1), umax64(a2, a3)),
                                  umax64(umax64(a4, a5), umax64(a6, a7)));
    int besti = (int)(~(unsigned int)bk);
    ax = muL[besti * 3 + 0]; ay = muL[besti * 3 + 1]; az = muL[besti * 3 + 2];
    if (t == 0) {
      float aa = ax * ax + ay * ay + az * az;
      float4 st = {ax, ay, az, aa};
      *(float4*)(anchors + ((size_t)b * KP_ + k) * 4) = st;
    }
  }
  for (int k = K_ + t; k < KP_; k += 512) {
    float4 z4 = {0.f, 0.f, 0.f, 0.f};
    *(float4*)(anchors + ((size_t)b * KP_ + k) * 4) = z4;
  }
}

// =====================================================================
// spatial logits + mask + softmax, in place over A (holds Lsem).
__global__ __launch_bounds__(256) void spatial_softmax_k(
    const float* __restrict__ mu, const float* __restrict__ mask,
    const float* __restrict__ anchors, const float* __restrict__ lsm_p,
    const float* __restrict__ wsem_p, const float* __restrict__ wmu_p,
    float* __restrict__ A) {
  const int bid = blockIdx.x;
  const int b = bid >> 11;
  const int n0 = (bid & 2047) * 4;
  const int tid = threadIdx.x;
  const int wv = tid >> 6;
  const int lane = tid & 63;
  __shared__ __align__(16) float anch_lds[KP_][4];
  for (int q = tid; q < KP_; q += 256)
    *(float4*)(&anch_lds[q][0]) = *(const float4*)(anchors + ((size_t)b * KP_ + q) * 4);
  __syncthreads();

  const float sg = fmaxf(expf(lsm_p[0]), 1e-4f);
  const float inv2s2 = 0.5f / (sg * sg);
  const float wsem = wsem_p[0];
  const float wmu = wmu_p[0];

  const size_t gr = (size_t)b * N_ + n0 + wv;
  const float* mp = mu + gr * 3;
  float x = mp[0], y = mp[1], z = mp[2];
  float mq = x * x + y * y + z * z;
  float mk = mask[gr];
  float* Arow = A + gr * K_;

  float v[11];
  float m = -3e38f;
#pragma unroll
  for (int j = 0; j < 11; j++) {
    int k = lane + 64 * j;
    if (k < K_) {
      float lsem = Arow[k];
      float4 a4 = *(const float4*)(&anch_lds[k][0]);
      float tdot = x * a4.x + y * a4.y + z * a4.z;
      float d2 = mq - 2.f * tdot + a4.w;
      float l = wsem * lsem - wmu * d2 * inv2s2;
      if (mk < 0.5f) l = -1e9f;
      v[j] = l;
    } else v[j] = -1e30f;
    m = fmaxf(m, v[j]);
  }
  for (int off = 32; off; off >>= 1) m = fmaxf(m, __shfl_xor(m, off));
  float sum = 0.f;
#pragma unroll
  for (int j = 0; j < 11; j++) { float e = expf(v[j] - m); v[j] = e; sum += e; }
  for (int off = 32; off; off >>= 1) sum += __shfl_xor(sum, off);
  float r = mk / sum;
#pragma unroll
  for (int j = 0; j < 11; j++) {
    int k = lane + 64 * j;
    if (k < K_) Arow[k] = v[j] * r;
  }
}

// =====================================================================
// Transpose A fp32 [b][n][683] -> At bf16 [b][768][8192] (pad rows zero)
__global__ __launch_bounds__(256) void transpose_at_k(const float* __restrict__ A,
    unsigned short* __restrict__ At) {
  const int bid = blockIdx.x;          // b(4) * ktile(12) * ntile(128)
  const int ntile = bid % 128;
  const int rem = bid / 128;
  const int kt = rem % 12;
  const int b = rem / 12;
  const int k0 = kt * 64, n0 = ntile * 64;
  const int tid = threadIdx.x;
  __shared__ __align__(16) unsigned short T[64][72];

  {
    const int n_loc = tid >> 4;        // 0..15
    const int k4 = (tid & 15) * 4;
#pragma unroll
    for (int nn = 0; nn < 4; nn++) {
      int n = n_loc + 16 * nn;
      const float* ar = A + ((size_t)(b * N_ + n0 + n)) * K_;
#pragma unroll
      for (int q = 0; q < 4; q++) {
        int kk = k0 + k4 + q;
        float f = (kk < K_) ? ar[kk] : 0.f;
        T[k4 + q][n] = f2bf_rne(f);
      }
    }
  }
  __syncthreads();
  {
    const int k_loc = tid >> 2;        // 0..63
    const int c = tid & 3;             // 16-ushort chunk
    uint4 v0 = *(const uint4*)(&T[k_loc][c * 16]);
    uint4 v1 = *(const uint4*)(&T[k_loc][c * 16 + 8]);
    unsigned short* dst = At + ((size_t)(b * KP_ + k0 + k_loc)) * N_ + n0 + c * 16;
    *(uint4*)dst = v0;
    *(uint4*)(dst + 8) = v1;
  }
}

// =====================================================================
// MFMA gram + fused collapse-loss tile partial.
// 84 blocks = 4 b x 21 symmetric 128x128 tiles; full N reduction per block.
__global__ __launch_bounds__(256) void gram_mfma_k(const unsigned short* __restrict__ At,
    const float* __restrict__ norm_ws, float* __restrict__ lossp) {
  const int bid = blockIdx.x;
  const int b = bid / 21;
  int p = bid % 21;
  int tk = 0, tl = 0;
  { int pp = p; for (int r0 = 0; r0 < 6; r0++) { int cnt = 6 - r0; if (pp < cnt) { tk = r0; tl = r0 + pp; break; } pp -= cnt; } }
  const int k0 = tk * 128, l0 = tl * 128;
  const int tid = threadIdx.x;
  const int l = tid & 63;
  const int w = tid >> 6;
  const int wr = w >> 1, wc = w & 1;

  __shared__ __align__(16) unsigned short Ak_lds[128 * 72];
  __shared__ __align__(16) unsigned short Al_lds[128 * 72];
  __shared__ float nk_s[128], nl_s[128], red_s[4];

  if (tid < 128) {
    int kk = k0 + tid;
    nk_s[tid] = (kk < K_) ? fmaxf(norm_ws[b * KT_ + kk], 1e-8f) : 1.f;
  } else {
    int ll2 = l0 + tid - 128;
    nl_s[tid - 128] = (ll2 < K_) ? fmaxf(norm_ws[b * KT_ + ll2], 1e-8f) : 1.f;
  }

  f32x4 acc[4][4];
#pragma unroll
  for (int i = 0; i < 4; i++)
#pragma unroll
    for (int j = 0; j < 4; j++) acc[i][j] = (f32x4){0.f, 0.f, 0.f, 0.f};

  const unsigned short* gk = At + ((size_t)(b * KP_ + k0)) * N_;
  const unsigned short* gl = At + ((size_t)(b * KP_ + l0)) * N_;

  for (int ch = 0; ch < 128; ch++) {
    const int n0 = ch * 64;
    __syncthreads();
#pragma unroll
    for (int q = 0; q < 4; q++) {
      int chunk = tid + 256 * q;
      int row = chunk >> 3, slot = chunk & 7;
      uint4 v = *(const uint4*)(gk + (size_t)row * N_ + n0 + slot * 8);
      *(uint4*)(Ak_lds + row * 72 + slot * 8) = v;
      uint4 v2 = *(const uint4*)(gl + (size_t)row * N_ + n0 + slot * 8);
      *(uint4*)(Al_lds + row * 72 + slot * 8) = v2;
    }
    __syncthreads();
#pragma unroll
    for (int ks = 0; ks < 2; ks++) {
      const int noff = (l >> 4) * 8 + ks * 32;
      bf16x8s af[4], bfr[4];
#pragma unroll
      for (int f = 0; f < 4; f++) {
        af[f]  = *(const bf16x8s*)(Ak_lds + (wr * 64 + f * 16 + (l & 15)) * 72 + noff);
        bfr[f] = *(const bf16x8s*)(Al_lds + (wc * 64 + f * 16 + (l & 15)) * 72 + noff);
      }
#pragma unroll
      for (int i = 0; i < 4; i++)
#pragma unroll
        for (int j = 0; j < 4; j++)
          acc[i][j] = __builtin_amdgcn_mfma_f32_16x16x32_bf16(af[i], bfr[j], acc[i][j], 0, 0, 0);
    }
  }

  // epilogue: loss partial for this tile
  float local = 0.f;
  const float wgt = (tk == tl) ? 1.f : 2.f;
#pragma unroll
  for (int i = 0; i < 4; i++) {
#pragma unroll
    for (int j = 0; j < 4; j++) {
#pragma unroll
      for (int r = 0; r < 4; r++) {
        int ki = wr * 64 + i * 16 + (l >> 4) * 4 + r;   // local row
        int li = wc * 64 + j * 16 + (l & 15);           // local col
        int gkk = k0 + ki, gll = l0 + li;
        if (gkk < K_ && gll < K_ && gkk != gll) {
          float g = acc[i][j][r];
          float x = g / (nk_s[ki] * nl_s[li]);
          local = fmaf(wgt * x, x, local);
        }
      }
    }
  }
  for (int off = 32; off; off >>= 1) local += __shfl_xor(local, off);
  if ((tid & 63) == 0) red_s[w] = local;
  __syncthreads();
  if (tid == 0) lossp[bid] = red_s[0] + red_s[1] + red_s[2] + red_s[3];
}

// =====================================================================
// GEMM2: moments = A^T x F, F = [s(128) | ext(16) | pad(16)], plus sum(A^2).
__global__ __launch_bounds__(256) void gemm2_k(const float* __restrict__ A,
    const float* __restrict__ s, const float* __restrict__ ext,
    float* __restrict__ part) {
  const int bid = blockIdx.x;
  const int np = bid / 44;
  const int rem = bid % 44;
  const int b = rem / 11;
  const int k0 = (rem % 11) * 64;
  const int n0 = np * 1024;
  const int tid = threadIdx.x;
  const int kt = tid & 15;
  const int ft = tid >> 4;
  __shared__ __align__(16) float A_lds[32][64];
  __shared__ __align__(16) float F_lds[32][160];
  float acc[4][10];
#pragma unroll
  for (int c = 0; c < 4; c++)
#pragma unroll
    for (int f = 0; f < 10; f++) acc[c][f] = 0.f;
  float asq[4] = {0.f, 0.f, 0.f, 0.f};

  for (int ch = 0; ch < 32; ch++) {
    int nb = n0 + ch * 32;
    __syncthreads();
#pragma unroll
    for (int p = 0; p < 8; p++) {
      int q = tid + 256 * p; int r = q >> 6; int c = q & 63; int k = k0 + c;
      A_lds[r][c] = (k < K_) ? A[((size_t)(b * N_ + nb + r)) * K_ + k] : 0.f;
    }
#pragma unroll
    for (int p = 0; p < 16; p++) {
      int q = tid + 256 * p; int r = q >> 7; int c = q & 127;
      F_lds[r][c] = s[((size_t)(b * N_ + nb + r)) * C_ + c];
    }
#pragma unroll
    for (int p = 0; p < 2; p++) {
      int q = tid + 256 * p; int r = q >> 4; int e = q & 15;
      F_lds[r][128 + e] = ext[((size_t)(b * N_ + nb + r)) * 16 + e];
      F_lds[r][144 + e] = 0.f;
    }
    __syncthreads();
#pragma unroll
    for (int i = 0; i < 32; i++) {
      float a0 = A_lds[i][kt * 4 + 0];
      float a1 = A_lds[i][kt * 4 + 1];
      float a2 = A_lds[i][kt * 4 + 2];
      float a3 = A_lds[i][kt * 4 + 3];
      if (ft == 0) {
        asq[0] = fmaf(a0, a0, asq[0]); asq[1] = fmaf(a1, a1, asq[1]);
        asq[2] = fmaf(a2, a2, asq[2]); asq[3] = fmaf(a3, a3, asq[3]);
      }
#pragma unroll
      for (int f = 0; f < 10; f++) {
        float fv = F_lds[i][ft * 10 + f];
        acc[0][f] = fmaf(a0, fv, acc[0][f]);
        acc[1][f] = fmaf(a1, fv, acc[1][f]);
        acc[2][f] = fmaf(a2, fv, acc[2][f]);
        acc[3][f] = fmaf(a3, fv, acc[3][f]);
      }
    }
  }
#pragma unroll
  for (int c = 0; c < 4; c++) {
    size_t base = ((size_t)((np * 4 + b) * KT_ + k0 + kt * 4 + c)) * 168;
#pragma unroll
    for (int f = 0; f < 10; f++) part[base + ft * 10 + f] = acc[c][f];
    if (ft == 0) part[base + 160] = asq[c];
  }
}

// =====================================================================
// Postprocess: one wave per (b,k): s_c, mu_c, Sigma_c, sumA, norms.
__global__ __launch_bounds__(256) void postproc_k(const float* __restrict__ part,
    float* __restrict__ out, float* __restrict__ sumA_ws, float* __restrict__ norm_ws) {
  const int gw = blockIdx.x * 4 + (threadIdx.x >> 6);
  const int lane = threadIdx.x & 63;
  const int b = gw / K_;
  const int k = gw % K_;
  float v0 = 0.f, v1 = 0.f, v2 = 0.f, v3 = 0.f;
  for (int np = 0; np < 8; np++) {
    const float* r = part + ((size_t)((np * 4 + b) * KT_ + k)) * 168;
    v0 += r[lane];
    v1 += r[64 + lane];
    if (lane < 16) v2 += r[128 + lane];
    if (lane == 0) v3 += r[160];
  }
  float sumA = __shfl(v2, 15);
  float asq = __shfl(v3, 0);
  float denom = fmaxf(sumA, 1e-8f);
  float inv = 1.f / denom;
  out[OUT_SC + ((size_t)(b * K_ + k)) * C_ + lane] = v0 * inv;
  out[OUT_SC + ((size_t)(b * K_ + k)) * C_ + 64 + lane] = v1 * inv;
  float m0 = __shfl(v2, 0) * inv;
  float m1 = __shfl(v2, 1) * inv;
  float m2 = __shfl(v2, 2) * inv;
  if (lane < 3) out[OUT_MUC + ((size_t)(b * K_ + k)) * 3 + lane] = (lane == 0) ? m0 : ((lane == 1) ? m1 : m2);
  float W = sumA * inv;
  float fac = 2.f - W;
  float M2s[6], Sgs[6];
#pragma unroll
  for (int j = 0; j < 6; j++) { M2s[j] = __shfl(v2, 3 + j); Sgs[j] = __shfl(v2, 9 + j); }
  if (lane < 9) {
    int d = lane / 3, e = lane % 3;
    int lo = min(d, e), hi = max(d, e);
    int j = hi + 2 * lo - ((lo * (lo - 1)) >> 1);
    float mud = (d == 0) ? m0 : ((d == 1) ? m1 : m2);
    float mue = (e == 0) ? m0 : ((e == 1) ? m1 : m2);
    float M2j = (j == 0) ? M2s[0] : (j == 1) ? M2s[1] : (j == 2) ? M2s[2] : (j == 3) ? M2s[3] : (j == 4) ? M2s[4] : M2s[5];
    float Sgj = (j == 0) ? Sgs[0] : (j == 1) ? Sgs[1] : (j == 2) ? Sgs[2] : (j == 3) ? Sgs[3] : (j == 4) ? Sgs[4] : Sgs[5];
    float val = (Sgj + M2j) * inv - mud * mue * fac;
    if (d == e) val += 1e-6f;
    out[OUT_SGC + ((size_t)(b * K_ + k)) * 9 + lane] = val;
  }
  if (lane == 0) { sumA_ws[b * KT_ + k] = sumA; norm_ws[b * KT_ + k] = sqrtf(asq); }
}

// =====================================================================
// OLD fp32 gram path (fallback if ws too small for At)
__device__ __forceinline__ int swz(int f) { return f ^ (((f >> 5) & 3) << 3); }

__global__ __launch_bounds__(256) void gram_k(const float* __restrict__ A,
                                              float* __restrict__ Gpart) {
  const int bid = blockIdx.x;
  const int np = bid & 1;
  int q = bid >> 1;
  const int b = q / 21;
  int p = q % 21;
  int tk = 0, tl = 0;
  { int pp = p; for (int r0 = 0; r0 < 6; r0++) { int cnt = 6 - r0; if (pp < cnt) { tk = r0; tl = r0 + pp; break; } pp -= cnt; } }
  const int k0 = tk * 128, l0 = tl * 128;
  const int n0 = np * 4096;
  const int tid = threadIdx.x;
  const int ktid = tid & 15, ltid = tid >> 4;
  const bool diag = (tk == tl);
  __shared__ __align__(16) float Ak[32][128];
  __shared__ __align__(16) float Al[32][128];
  float acc[8][8];
#pragma unroll
  for (int i = 0; i < 8; i++)
#pragma unroll
    for (int j = 0; j < 8; j++) acc[i][j] = 0.f;

  const int kb = swz(ktid * 8);
  const int lb = swz(ltid * 8);
  for (int ch = 0; ch < 128; ch++) {
    int nb = n0 + ch * 32;
    __syncthreads();
#pragma unroll
    for (int pq = 0; pq < 16; pq++) {
      int qq = tid + 256 * pq; int r = qq >> 7; int c = qq & 127;
      int kk = k0 + c;
      Ak[r][swz(c)] = (kk < K_) ? A[((size_t)(b * N_ + nb + r)) * K_ + kk] : 0.f;
      if (!diag) {
        int ll = l0 + c;
        Al[r][swz(c)] = (ll < K_) ? A[((size_t)(b * N_ + nb + r)) * K_ + ll] : 0.f;
      }
    }
    __syncthreads();
    const float (*Alp)[128] = diag ? Ak : Al;
#pragma unroll
    for (int i = 0; i < 32; i++) {
      float4 ka = *(const float4*)(&Ak[i][kb]);
      float4 kb4 = *(const float4*)(&Ak[i][kb + 4]);
      float4 la = *(const float4*)(&Alp[i][lb]);
      float4 lb4 = *(const float4*)(&Alp[i][lb + 4]);
      float av[8] = {ka.x, ka.y, ka.z, ka.w, kb4.x, kb4.y, kb4.z, kb4.w};
      float lv[8] = {la.x, la.y, la.z, la.w, lb4.x, lb4.y, lb4.z, lb4.w};
#pragma unroll
      for (int ii = 0; ii < 8; ii++)
#pragma unroll
        for (int jj = 0; jj < 8; jj++)
          acc[ii][jj] = fmaf(av[ii], lv[jj], acc[ii][jj]);
    }
  }
#pragma unroll
  for (int ii = 0; ii < 8; ii++) {
    int kk = k0 + ktid * 8 + ii;
    float* gp = Gpart + ((size_t)((np * 4 + b) * KP_ + kk)) * KP_ + l0 + ltid * 8;
#pragma unroll
    for (int jj = 0; jj < 8; jj++) gp[jj] = acc[ii][jj];
  }
}

__global__ __launch_bounds__(256) void loss_part_k(const float* __restrict__ Gpart,
    const float* __restrict__ norm_ws, float* __restrict__ lossp) {
  const long long total = (long long)B_ * 21 * 16384;
  float local = 0.f;
  for (long long idx = (long long)blockIdx.x * 256 + threadIdx.x; idx < total; idx += (long long)512 * 256) {
    int e = (int)(idx & 16383);
    int rest = (int)(idx >> 14);
    int p = rest % 21;
    int b = rest / 21;
    int tk = 0, tl = 0;
    { int pp = p; for (int r0 = 0; r0 < 6; r0++) { int cnt = 6 - r0; if (pp < cnt) { tk = r0; tl = r0 + pp; break; } pp -= cnt; } }
    int i = e >> 7, j = e & 127;
    int k = tk * 128 + i, l = tl * 128 + j;
    if (k < K_ && l < K_ && k != l) {
      size_t i0 = ((size_t)((0 * 4 + b) * KP_ + k)) * KP_ + l;
      size_t i1 = ((size_t)((1 * 4 + b) * KP_ + k)) * KP_ + l;
      float g = Gpart[i0] + Gpart[i1];
      float nk = fmaxf(norm_ws[b * KT_ + k], 1e-8f);
      float nl2 = fmaxf(norm_ws[b * KT_ + l], 1e-8f);
      float x = g / (nk * nl2);
      float wgt = (tk == tl) ? 1.f : 2.f;
      local = fmaf(wgt * x, x, local);
    }
  }
  __shared__ float red[4];
  for (int off = 32; off; off >>= 1) local += __shfl_xor(local, off);
  if ((threadIdx.x & 63) == 0) red[threadIdx.x >> 6] = local;
  __syncthreads();
  if (threadIdx.x == 0) lossp[blockIdx.x] = red[0] + red[1] + red[2] + red[3];
}

__global__ __launch_bounds__(256) void final_k(const float* __restrict__ sumA_ws,
    const float* __restrict__ lossp, float* __restrict__ out) {
  const int lane = threadIdx.x & 63;
  const int wv = threadIdx.x >> 6;
  __shared__ float occ_s[4];
  __shared__ float col_s[4];
  float sb = 0.f;
  for (int k = lane; k < K_; k += 64) sb += sumA_ws[wv * KT_ + k];
  for (int off = 32; off; off >>= 1) sb += __shfl_xor(sb, off);
  float Sb = fmaxf(sb, 1e-8f);
  float lo = 0.f;
  const float tgt = 1.f / (float)K_;
  for (int k = lane; k < K_; k += 64) {
    float o = sumA_ws[wv * KT_ + k] / Sb - tgt;
    lo = fmaf(o, o, lo);
  }
  for (int off = 32; off; off >>= 1) lo += __shfl_xor(lo, off);
  if (lane == 0) occ_s[wv] = lo;
  float c = lossp[threadIdx.x] + lossp[threadIdx.x + 256];
  for (int off = 32; off; off >>= 1) c += __shfl_xor(c, off);
  if (lane == 0) col_s[wv] = c;
  __syncthreads();
  if (threadIdx.x == 0) {
    float loss_occ = (occ_s[0] + occ_s[1] + occ_s[2] + occ_s[3]) / (float)(B_ * K_);
    float coll = (col_s[0] + col_s[1] + col_s[2] + col_s[3]) / ((float)B_ * K_ * K_);
    out[OUT_TOT] = loss_occ + 0.1f * coll;
  }
}

// final for the MFMA path: 84 tile partials
__global__ __launch_bounds__(256) void final2_k(const float* __restrict__ sumA_ws,
    const float* __restrict__ lossp, float* __restrict__ out) {
  const int lane = threadIdx.x & 63;
  const int wv = threadIdx.x >> 6;
  __shared__ float occ_s[4];
  __shared__ float col_s[4];
  float sb = 0.f;
  for (int k = lane; k < K_; k += 64) sb += sumA_ws[wv * KT_ + k];
  for (int off = 32; off; off >>= 1) sb += __shfl_xor(sb, off);
  float Sb = fmaxf(sb, 1e-8f);
  float lo = 0.f;
  const float tgt = 1.f / (float)K_;
  for (int k = lane; k < K_; k += 64) {
    float o = sumA_ws[wv * KT_ + k] / Sb - tgt;
    lo = fmaf(o, o, lo);
  }
  for (int off = 32; off; off >>= 1) lo += __shfl_xor(lo, off);
  if (lane == 0) occ_s[wv] = lo;
  float c = 0.f;
  for (int i = threadIdx.x; i < 84; i += 256) c += lossp[i];
  for (int off = 32; off; off >>= 1) c += __shfl_xor(c, off);
  if (lane == 0) col_s[wv] = c;
  __syncthreads();
  if (threadIdx.x == 0) {
    float loss_occ = (occ_s[0] + occ_s[1] + occ_s[2] + occ_s[3]) / (float)(B_ * K_);
    float coll = (col_s[0] + col_s[1] + col_s[2] + col_s[3]) / ((float)B_ * K_ * K_);
    out[OUT_TOT] = loss_occ + 0.1f * coll;
  }
}

// =====================================================================
extern "C" void kernel_launch(void* const* d_in, const int* in_sizes, int n_in,
                              void* d_out, int out_size, void* d_ws, size_t ws_size,
                              hipStream_t stream) {
  const float* s = (const float*)d_in[0];
  const float* mu = (const float*)d_in[1];
  const float* Sigma = (const float*)d_in[2];
  const float* mask = (const float*)d_in[3];
  const float* Wp = (const float*)d_in[4];
  const float* se = (const float*)d_in[5];
  const float* lsm = (const float*)d_in[6];
  const float* wsem = (const float*)d_in[7];
  const float* wmu = (const float*)d_in[8];
  float* out = (float*)d_out;
  float* ws = (float*)d_ws;

  float* ET = ws + WS_ET;
  float* anch = ws + WS_ANCH;
  float* ext = ws + WS_EXT;
  float* part = ws + WS_PART;
  float* sumA = ws + WS_SUMA;
  float* nrm = ws + WS_NORM;

  hipLaunchKernelGGL(build_ET_k, dim3(384), dim3(256), 0, stream, Wp, se, ET);
  hipLaunchKernelGGL(fused_k, dim3(1092), dim3(512), 0, stream, s, mu, Sigma, mask, ET, anch, ext, out);
  hipLaunchKernelGGL(spatial_softmax_k, dim3(8192), dim3(256), 0, stream, mu, mask, anch, lsm, wsem, wmu, out);
  hipLaunchKernelGGL(gemm2_k, dim3(352), dim3(256), 0, stream, out, s, ext, part);
  hipLaunchKernelGGL(postproc_k, dim3(683), dim3(256), 0, stream, part, out, sumA, nrm);

  const bool use_mfma = ws_size >= (size_t)WS_NEW_END * 4;
  if (use_mfma) {
    float* lossp2 = ws + WS_LOSSP2;
    unsigned short* At = (unsigned short*)(ws + WS_AT);
    hipLaunchKernelGGL(transpose_at_k, dim3(4 * 12 * 128), dim3(256), 0, stream, out, At);
    hipLaunchKernelGGL(gram_mfma_k, dim3(84), dim3(256), 0, stream, At, nrm, lossp2);
    hipLaunchKernelGGL(final2_k, dim3(1), dim3(256), 0, stream, sumA, lossp2, out);
  } else {
    float* Gpart = ws + WS_GPART;
    float* lossp = ws + WS_LOSSP;
    hipLaunchKernelGGL(gram_k, dim3(168), dim3(256), 0, stream, out, Gpart);
    hipLaunchKernelGGL(loss_part_k, dim3(512), dim3(256), 0, stream, Gpart, nrm, lossp);
    hipLaunchKernelGGL(final_k, dim3(1), dim3(256), 0, stream, sumA, lossp, out);
  }
}